// Round 1
// baseline (1757.188 us; speedup 1.0000x reference)
//
#include <hip/hip_runtime.h>
#include <cstdint>

#define N_NODES 100000
#define EP_N 400000
#define EN_N 400000

// ws float offsets
#define ACC_OFF 0
#define CNTP_OFF 16
#define CNTN_OFF (16 + N_NODES)
#define BUF_OFF (16 + 2 * N_NODES)
#define BUF_SZ (64 * N_NODES)

__global__ void count_kernel(const int* __restrict__ pe, const int* __restrict__ ne,
                             float* cp, float* cn) {
    int i = blockIdx.x * 256 + threadIdx.x;
    if (i < EP_N) {
        atomicAdd(&cp[pe[i]], 1.0f);
    } else if (i < EP_N + EN_N) {
        atomicAdd(&cn[ne[i - EP_N]], 1.0f);
    }
}

// one thread per (edge, dim): gather X[col][d], atomic-add to agg[row][d]
__global__ void base_scatter(const float* __restrict__ X,
                             const int* __restrict__ pe, const int* __restrict__ ne,
                             float* aggP, float* aggN) {
    long long idx = (long long)blockIdx.x * 256 + threadIdx.x;
    long long e = idx >> 6;
    int d = (int)(idx & 63);
    if (e < EP_N) {
        int row = pe[e], col = pe[EP_N + e];
        atomicAdd(&aggP[(long long)row * 64 + d], X[(long long)col * 64 + d]);
    } else if (e < EP_N + EN_N) {
        long long e2 = e - EP_N;
        int row = ne[e2], col = ne[EN_N + e2];
        atomicAdd(&aggN[(long long)row * 64 + d], X[(long long)col * 64 + d]);
    }
}

// deep layer: pos edges scatter h_pos->A, h_neg->C ; neg edges scatter h_neg->B, h_pos->D
__global__ void deep_scatter(const float* __restrict__ hp, const float* __restrict__ hn,
                             const int* __restrict__ pe, const int* __restrict__ ne,
                             float* A, float* B, float* C, float* Dd) {
    long long idx = (long long)blockIdx.x * 256 + threadIdx.x;
    long long e = idx >> 6;
    int d = (int)(idx & 63);
    if (e < EP_N) {
        int row = pe[e], col = pe[EP_N + e];
        float vp = hp[(long long)col * 64 + d];
        float vn = hn[(long long)col * 64 + d];
        atomicAdd(&A[(long long)row * 64 + d], vp);
        atomicAdd(&C[(long long)row * 64 + d], vn);
    } else if (e < EP_N + EN_N) {
        long long e2 = e - EP_N;
        int row = ne[e2], col = ne[EN_N + e2];
        float vn = hn[(long long)col * 64 + d];
        float vp = hp[(long long)col * 64 + d];
        atomicAdd(&B[(long long)row * 64 + d], vn);
        atomicAdd(&Dd[(long long)row * 64 + d], vp);
    }
}

// h = tanh([agg/cnt, X] @ W + b)  with W [128][64]; wave of 64 = 64 nodes, lane = node.
__global__ __launch_bounds__(64) void base_gemm(
    const float* __restrict__ agg, const float* __restrict__ cnt,
    const float* __restrict__ X, const float* __restrict__ W,
    const float* __restrict__ b, float* __restrict__ out) {
    __shared__ float in_lds[64 * 129];
    __shared__ float rcps[64];
    int lane = threadIdx.x;
    int base = blockIdx.x * 64;
    int nrem = N_NODES - base;
    if (nrem > 64) nrem = 64;
    if (lane < nrem) rcps[lane] = 1.0f / fmaxf(cnt[base + lane], 1.0f);
    __syncthreads();
    for (int i = lane; i < nrem * 128; i += 64) {
        int r = i >> 7, k = i & 127;
        float v = (k < 64) ? agg[(long long)(base + r) * 64 + k] * rcps[r]
                           : X[(long long)(base + r) * 64 + (k - 64)];
        in_lds[r * 129 + k] = v;
    }
    __syncthreads();
    float acc[64];
#pragma unroll
    for (int j = 0; j < 64; ++j) acc[j] = 0.0f;
    const float* row = &in_lds[lane * 129];
    for (int k = 0; k < 128; ++k) {
        float v = row[k];
#pragma unroll
        for (int j = 0; j < 64; ++j) acc[j] = fmaf(v, W[k * 64 + j], acc[j]);
    }
    if (lane < nrem) {
        float* o = out + (long long)(base + lane) * 64;
#pragma unroll
        for (int j = 0; j < 64; ++j) o[j] = tanhf(acc[j] + b[j]);
    }
}

// z[:, colOff..colOff+31] = tanh([aggP/cntP, aggN/cntN, prev] @ W + b), W [192][32]
__global__ __launch_bounds__(64) void deep_gemm(
    const float* __restrict__ aggP, const float* __restrict__ aggN,
    const float* __restrict__ prev, const float* __restrict__ cntP,
    const float* __restrict__ cntN, const float* __restrict__ W,
    const float* __restrict__ b, float* __restrict__ zout, int colOff) {
    __shared__ float in_lds[64 * 193];
    __shared__ float rcpP[64], rcpN[64];
    int lane = threadIdx.x;
    int base = blockIdx.x * 64;
    int nrem = N_NODES - base;
    if (nrem > 64) nrem = 64;
    if (lane < nrem) {
        rcpP[lane] = 1.0f / fmaxf(cntP[base + lane], 1.0f);
        rcpN[lane] = 1.0f / fmaxf(cntN[base + lane], 1.0f);
    }
    __syncthreads();
    for (int i = lane; i < nrem * 192; i += 64) {
        int r = i / 192, k = i - r * 192;
        float v;
        if (k < 64)
            v = aggP[(long long)(base + r) * 64 + k] * rcpP[r];
        else if (k < 128)
            v = aggN[(long long)(base + r) * 64 + (k - 64)] * rcpN[r];
        else
            v = prev[(long long)(base + r) * 64 + (k - 128)];
        in_lds[r * 193 + k] = v;
    }
    __syncthreads();
    float acc[32];
#pragma unroll
    for (int j = 0; j < 32; ++j) acc[j] = 0.0f;
    const float* row = &in_lds[lane * 193];
    for (int k = 0; k < 192; ++k) {
        float v = row[k];
#pragma unroll
        for (int j = 0; j < 32; ++j) acc[j] = fmaf(v, W[k * 32 + j], acc[j]);
    }
    if (lane < nrem) {
        float* o = zout + (long long)(base + lane) * 64 + colOff;
#pragma unroll
        for (int j = 0; j < 32; ++j) o[j] = tanhf(acc[j] + b[j]);
    }
}

// wave per edge: triplet norms + 2-class log-softmax regression, fused
__global__ __launch_bounds__(256) void loss_kernel(
    const float* __restrict__ z, const int* __restrict__ pe, const int* __restrict__ ne,
    const int* __restrict__ ps, const int* __restrict__ ns, const int* __restrict__ tgt,
    const float* __restrict__ Wreg, float* acc) {
    int lane = threadIdx.x & 63;
    int wid = (blockIdx.x * 256 + threadIdx.x) >> 6;
    int nw = (gridDim.x * 256) >> 6;
    float w0i = Wreg[lane * 2 + 0], w1i = Wreg[lane * 2 + 1];
    float w0j = Wreg[(64 + lane) * 2 + 0], w1j = Wreg[(64 + lane) * 2 + 1];
    float s_p = 0.f, s_n = 0.f, s_r = 0.f;
    for (int e = wid; e < EP_N + EN_N; e += nw) {
        int i, j, k;
        bool isp = (e < EP_N);
        if (isp) {
            i = pe[e]; j = pe[EP_N + e]; k = ps[e];
        } else {
            int e2 = e - EP_N;
            i = ne[e2]; j = ne[EN_N + e2]; k = ns[e2];
        }
        int t = tgt[e];
        float zi = z[(long long)i * 64 + lane];
        float zj = z[(long long)j * 64 + lane];
        float zk = z[(long long)k * 64 + lane];
        float dij = zi - zj, djk = zj - zk;
        float nij = dij * dij, nik = djk * djk;
        float l0 = zi * w0i + zj * w0j;
        float l1 = zi * w1i + zj * w1j;
#pragma unroll
        for (int off = 32; off > 0; off >>= 1) {
            nij += __shfl_xor(nij, off);
            nik += __shfl_xor(nik, off);
            l0 += __shfl_xor(l0, off);
            l1 += __shfl_xor(l1, off);
        }
        float m = fmaxf(l0, l1);
        float lse = m + logf(expf(l0 - m) + expf(l1 - m));
        float lt = t ? l1 : l0;
        float tri = fmaxf(nij - nik, 0.0f);
        s_r += (lse - lt);
        if (isp) s_p += tri; else s_n += tri;
    }
    __shared__ float red[3][4];
    int w = threadIdx.x >> 6;
    if (lane == 0) {
        red[0][w] = s_p; red[1][w] = s_n; red[2][w] = s_r;
    }
    __syncthreads();
    if (threadIdx.x == 0) {
        float a = red[0][0] + red[0][1] + red[0][2] + red[0][3];
        float bb = red[1][0] + red[1][1] + red[1][2] + red[1][3];
        float c = red[2][0] + red[2][1] + red[2][2] + red[2][3];
        atomicAdd(&acc[0], a);
        atomicAdd(&acc[1], bb);
        atomicAdd(&acc[2], c);
    }
}

__global__ void finalize_kernel(const float* __restrict__ acc, float* out) {
    out[0] = acc[2] / (float)(EP_N + EN_N) +
             1.0f * (acc[0] / (float)EP_N + acc[1] / (float)EN_N);
}

extern "C" void kernel_launch(void* const* d_in, const int* in_sizes, int n_in,
                              void* d_out, int out_size, void* d_ws, size_t ws_size,
                              hipStream_t stream) {
    const float* X = (const float*)d_in[0];
    const float* W_pos0 = (const float*)d_in[1];
    const float* b_pos0 = (const float*)d_in[2];
    const float* W_neg0 = (const float*)d_in[3];
    const float* b_neg0 = (const float*)d_in[4];
    const float* W_pos1 = (const float*)d_in[5];
    const float* b_pos1 = (const float*)d_in[6];
    const float* W_neg1 = (const float*)d_in[7];
    const float* b_neg1 = (const float*)d_in[8];
    const float* W_reg = (const float*)d_in[9];
    const int* pe = (const int*)d_in[10];
    const int* ne = (const int*)d_in[11];
    const int* target = (const int*)d_in[12];
    const int* ps = (const int*)d_in[13];
    const int* ns = (const int*)d_in[14];
    float* out = (float*)d_out;
    float* ws = (float*)d_ws;

    float* acc = ws + ACC_OFF;
    float* cp = ws + CNTP_OFF;
    float* cn = ws + CNTN_OFF;
    float* buf0 = ws + BUF_OFF;      // agg_pos -> A
    float* buf1 = buf0 + BUF_SZ;     // agg_neg -> B
    float* buf2 = buf1 + BUF_SZ;     // h_pos
    float* buf3 = buf2 + BUF_SZ;     // h_neg
    float* buf4 = buf3 + BUF_SZ;     // C
    float* buf5 = buf4 + BUF_SZ;     // D
    float* z = out + 1;

    // zero: acc + counts + buf0 + buf1 (contiguous)
    hipMemsetAsync(ws, 0, (size_t)(BUF_OFF + 2 * BUF_SZ) * sizeof(float), stream);

    count_kernel<<<(EP_N + EN_N + 255) / 256, 256, 0, stream>>>(pe, ne, cp, cn);
    base_scatter<<<(long long)(EP_N + EN_N) * 64 / 256, 256, 0, stream>>>(X, pe, ne, buf0, buf1);
    base_gemm<<<(N_NODES + 63) / 64, 64, 0, stream>>>(buf0, cp, X, W_pos0, b_pos0, buf2);
    base_gemm<<<(N_NODES + 63) / 64, 64, 0, stream>>>(buf1, cn, X, W_neg0, b_neg0, buf3);

    // re-zero buf0/buf1 (A,B) and buf4/buf5 (C,D)
    hipMemsetAsync(buf0, 0, (size_t)2 * BUF_SZ * sizeof(float), stream);
    hipMemsetAsync(buf4, 0, (size_t)2 * BUF_SZ * sizeof(float), stream);

    deep_scatter<<<(long long)(EP_N + EN_N) * 64 / 256, 256, 0, stream>>>(buf2, buf3, pe, ne,
                                                                          buf0, buf1, buf4, buf5);
    deep_gemm<<<(N_NODES + 63) / 64, 64, 0, stream>>>(buf0, buf1, buf2, cp, cn, W_pos1, b_pos1, z, 0);
    deep_gemm<<<(N_NODES + 63) / 64, 64, 0, stream>>>(buf4, buf5, buf3, cp, cn, W_neg1, b_neg1, z, 32);

    loss_kernel<<<1024, 256, 0, stream>>>(z, pe, ne, ps, ns, target, W_reg, acc);
    finalize_kernel<<<1, 1, 0, stream>>>(acc, out);
}

// Round 2
// 1087.465 us; speedup vs baseline: 1.6159x; 1.6159x over previous
//
#include <hip/hip_runtime.h>
#include <cstdint>

#define N_NODES 100000
#define EP_N 400000
#define EN_N 400000
#define NODE_BLOCKS ((N_NODES + 63) / 64)

// ws layout (in 4-byte units)
#define ACC_OFF 0                      // 16 floats
#define I_CNTP 16
#define I_CNTN (I_CNTP + N_NODES)
#define I_CURP (I_CNTN + N_NODES)
#define I_CURN (I_CURP + N_NODES)
#define I_OFFP (I_CURN + N_NODES)
#define I_OFFN (I_OFFP + N_NODES + 1)
#define I_CSRP (I_OFFN + N_NODES + 1)
#define I_CSRN (I_CSRP + EP_N)
#define F_BUF (((I_CSRN + EN_N) + 15) & ~15)
#define BUF_SZ (64 * N_NODES)

__global__ void count_kernel(const int* __restrict__ pe, const int* __restrict__ ne,
                             int* cp, int* cn) {
    int i = blockIdx.x * 256 + threadIdx.x;
    if (i < EP_N) {
        atomicAdd(&cp[pe[i]], 1);
    } else if (i < EP_N + EN_N) {
        atomicAdd(&cn[ne[i - EP_N]], 1);
    }
}

// one block per edge-list: exclusive scan of counts -> offsets (n = N_NODES)
__global__ __launch_bounds__(1024) void scan_kernel(const int* __restrict__ cntP,
                                                    const int* __restrict__ cntN,
                                                    int* offP, int* offN) {
    const int* cnt = blockIdx.x == 0 ? cntP : cntN;
    int* off = blockIdx.x == 0 ? offP : offN;
    const int n = N_NODES;
    const int chunk = (n + 1023) / 1024;  // 98
    int t = threadIdx.x;
    int beg = t * chunk;
    int end = beg + chunk < n ? beg + chunk : n;
    int s = 0;
    for (int i = beg; i < end; ++i) s += cnt[i];
    __shared__ int tmp[1024];
    tmp[t] = s;
    __syncthreads();
    for (int d = 1; d < 1024; d <<= 1) {
        int v = (t >= d) ? tmp[t - d] : 0;
        __syncthreads();
        tmp[t] += v;
        __syncthreads();
    }
    int running = tmp[t] - s;  // exclusive
    for (int i = beg; i < end; ++i) {
        off[i] = running;
        running += cnt[i];
    }
    if (beg < n && end == n) off[n] = running;
}

__global__ void fill_kernel(const int* __restrict__ pe, const int* __restrict__ ne,
                            const int* __restrict__ offP, const int* __restrict__ offN,
                            int* curP, int* curN, int* csrP, int* csrN) {
    int e = blockIdx.x * 256 + threadIdx.x;
    if (e < EP_N) {
        int row = pe[e], col = pe[EP_N + e];
        int slot = atomicAdd(&curP[row], 1);
        csrP[offP[row] + slot] = col;
    } else if (e < EP_N + EN_N) {
        int e2 = e - EP_N;
        int row = ne[e2], col = ne[EN_N + e2];
        int slot = atomicAdd(&curN[row], 1);
        csrN[offN[row] + slot] = col;
    }
}

// h = tanh([gather_mean(X, csr), X] @ W + b); block = 64 nodes, 256 threads.
__global__ __launch_bounds__(256) void base_fused(
    const float* __restrict__ X, const int* __restrict__ off,
    const int* __restrict__ csr, const float* __restrict__ W,
    const float* __restrict__ b, float* __restrict__ out) {
    __shared__ float in_lds[64 * 129];
    int tid = threadIdx.x, lane = tid & 63, w = tid >> 6;
    int base = blockIdx.x * 64;
    // phase 1: gather (wave w handles 16 nodes)
    for (int r = w * 16; r < w * 16 + 16; ++r) {
        int node = base + r;
        if (node < N_NODES) {
            int st = off[node], en = off[node + 1];
            float s0 = 0.f, s1 = 0.f;
            int p = st;
            for (; p + 1 < en; p += 2) {
                int c0 = csr[p], c1 = csr[p + 1];
                s0 += X[(long long)c0 * 64 + lane];
                s1 += X[(long long)c1 * 64 + lane];
            }
            if (p < en) s0 += X[(long long)csr[p] * 64 + lane];
            float rcp = 1.0f / fmaxf((float)(en - st), 1.0f);
            in_lds[r * 129 + lane] = (s0 + s1) * rcp;
            in_lds[r * 129 + 64 + lane] = X[(long long)node * 64 + lane];
        } else {
            in_lds[r * 129 + lane] = 0.f;
            in_lds[r * 129 + 64 + lane] = 0.f;
        }
    }
    __syncthreads();
    // phase 2: wave w computes output cols [16w, 16w+16); lane = node
    const float* Wp = W + __builtin_amdgcn_readfirstlane(w * 16);
    const float* bp = b + __builtin_amdgcn_readfirstlane(w * 16);
    float acc[16];
#pragma unroll
    for (int j = 0; j < 16; ++j) acc[j] = 0.f;
    const float* row = &in_lds[lane * 129];
    for (int k = 0; k < 128; ++k) {
        float v = row[k];
#pragma unroll
        for (int j = 0; j < 16; ++j) acc[j] = fmaf(v, Wp[k * 64 + j], acc[j]);
    }
#pragma unroll
    for (int j = 0; j < 16; ++j) acc[j] = tanhf(acc[j] + bp[j]);
    __syncthreads();
    // reuse in_lds as 64x65 out tile
    float* ot = in_lds;
#pragma unroll
    for (int j = 0; j < 16; ++j) ot[lane * 65 + w * 16 + j] = acc[j];
    __syncthreads();
    for (int i = tid; i < 64 * 64; i += 256) {
        int r = i >> 6, c = i & 63;
        int node = base + r;
        if (node < N_NODES) out[(long long)node * 64 + c] = ot[r * 65 + c];
    }
}

// zcols = tanh([gm(f1,csrP), gm(f2,csrN), f1] @ W + b); 32 cols at colOff
__global__ __launch_bounds__(256) void deep_fused(
    const float* __restrict__ f1, const float* __restrict__ f2,
    const int* __restrict__ offP, const int* __restrict__ csrP,
    const int* __restrict__ offN, const int* __restrict__ csrN,
    const float* __restrict__ W, const float* __restrict__ b,
    float* __restrict__ zout, int colOff) {
    __shared__ float in_lds[64 * 193];
    int tid = threadIdx.x, lane = tid & 63, w = tid >> 6;
    int base = blockIdx.x * 64;
    for (int r = w * 16; r < w * 16 + 16; ++r) {
        int node = base + r;
        if (node < N_NODES) {
            {
                int st = offP[node], en = offP[node + 1];
                float s0 = 0.f, s1 = 0.f;
                int p = st;
                for (; p + 1 < en; p += 2) {
                    int c0 = csrP[p], c1 = csrP[p + 1];
                    s0 += f1[(long long)c0 * 64 + lane];
                    s1 += f1[(long long)c1 * 64 + lane];
                }
                if (p < en) s0 += f1[(long long)csrP[p] * 64 + lane];
                in_lds[r * 193 + lane] = (s0 + s1) / fmaxf((float)(en - st), 1.0f);
            }
            {
                int st = offN[node], en = offN[node + 1];
                float s0 = 0.f, s1 = 0.f;
                int p = st;
                for (; p + 1 < en; p += 2) {
                    int c0 = csrN[p], c1 = csrN[p + 1];
                    s0 += f2[(long long)c0 * 64 + lane];
                    s1 += f2[(long long)c1 * 64 + lane];
                }
                if (p < en) s0 += f2[(long long)csrN[p] * 64 + lane];
                in_lds[r * 193 + 64 + lane] = (s0 + s1) / fmaxf((float)(en - st), 1.0f);
            }
            in_lds[r * 193 + 128 + lane] = f1[(long long)node * 64 + lane];
        } else {
            in_lds[r * 193 + lane] = 0.f;
            in_lds[r * 193 + 64 + lane] = 0.f;
            in_lds[r * 193 + 128 + lane] = 0.f;
        }
    }
    __syncthreads();
    const float* Wp = W + __builtin_amdgcn_readfirstlane(w * 8);
    const float* bp = b + __builtin_amdgcn_readfirstlane(w * 8);
    float acc[8];
#pragma unroll
    for (int j = 0; j < 8; ++j) acc[j] = 0.f;
    const float* row = &in_lds[lane * 193];
    for (int k = 0; k < 192; ++k) {
        float v = row[k];
#pragma unroll
        for (int j = 0; j < 8; ++j) acc[j] = fmaf(v, Wp[k * 32 + j], acc[j]);
    }
#pragma unroll
    for (int j = 0; j < 8; ++j) acc[j] = tanhf(acc[j] + bp[j]);
    __syncthreads();
    float* ot = in_lds;  // 64 x 33
#pragma unroll
    for (int j = 0; j < 8; ++j) ot[lane * 33 + w * 8 + j] = acc[j];
    __syncthreads();
    for (int i = tid; i < 64 * 32; i += 256) {
        int r = i >> 5, c = i & 31;
        int node = base + r;
        if (node < N_NODES) zout[(long long)node * 64 + colOff + c] = ot[r * 33 + c];
    }
}

// wave per edge: triplet norms + 2-class log-softmax regression, fused
__global__ __launch_bounds__(256) void loss_kernel(
    const float* __restrict__ z, const int* __restrict__ pe, const int* __restrict__ ne,
    const int* __restrict__ ps, const int* __restrict__ ns, const int* __restrict__ tgt,
    const float* __restrict__ Wreg, float* acc) {
    int lane = threadIdx.x & 63;
    int wid = (blockIdx.x * 256 + threadIdx.x) >> 6;
    int nw = (gridDim.x * 256) >> 6;
    float w0i = Wreg[lane * 2 + 0], w1i = Wreg[lane * 2 + 1];
    float w0j = Wreg[(64 + lane) * 2 + 0], w1j = Wreg[(64 + lane) * 2 + 1];
    float s_p = 0.f, s_n = 0.f, s_r = 0.f;
    for (int e = wid; e < EP_N + EN_N; e += nw) {
        int i, j, k;
        bool isp = (e < EP_N);
        if (isp) {
            i = pe[e]; j = pe[EP_N + e]; k = ps[e];
        } else {
            int e2 = e - EP_N;
            i = ne[e2]; j = ne[EN_N + e2]; k = ns[e2];
        }
        int t = tgt[e];
        float zi = z[(long long)i * 64 + lane];
        float zj = z[(long long)j * 64 + lane];
        float zk = z[(long long)k * 64 + lane];
        float dij = zi - zj, djk = zj - zk;
        float nij = dij * dij, nik = djk * djk;
        float l0 = zi * w0i + zj * w0j;
        float l1 = zi * w1i + zj * w1j;
#pragma unroll
        for (int off = 32; off > 0; off >>= 1) {
            nij += __shfl_xor(nij, off);
            nik += __shfl_xor(nik, off);
            l0 += __shfl_xor(l0, off);
            l1 += __shfl_xor(l1, off);
        }
        float m = fmaxf(l0, l1);
        float lse = m + logf(expf(l0 - m) + expf(l1 - m));
        float lt = t ? l1 : l0;
        float tri = fmaxf(nij - nik, 0.0f);
        s_r += (lse - lt);
        if (isp) s_p += tri; else s_n += tri;
    }
    __shared__ float red[3][4];
    int w = threadIdx.x >> 6;
    if (lane == 0) {
        red[0][w] = s_p; red[1][w] = s_n; red[2][w] = s_r;
    }
    __syncthreads();
    if (threadIdx.x == 0) {
        float a = red[0][0] + red[0][1] + red[0][2] + red[0][3];
        float bb = red[1][0] + red[1][1] + red[1][2] + red[1][3];
        float c = red[2][0] + red[2][1] + red[2][2] + red[2][3];
        atomicAdd(&acc[0], a);
        atomicAdd(&acc[1], bb);
        atomicAdd(&acc[2], c);
    }
}

__global__ void finalize_kernel(const float* __restrict__ acc, float* out) {
    out[0] = acc[2] / (float)(EP_N + EN_N) +
             1.0f * (acc[0] / (float)EP_N + acc[1] / (float)EN_N);
}

extern "C" void kernel_launch(void* const* d_in, const int* in_sizes, int n_in,
                              void* d_out, int out_size, void* d_ws, size_t ws_size,
                              hipStream_t stream) {
    const float* X = (const float*)d_in[0];
    const float* W_pos0 = (const float*)d_in[1];
    const float* b_pos0 = (const float*)d_in[2];
    const float* W_neg0 = (const float*)d_in[3];
    const float* b_neg0 = (const float*)d_in[4];
    const float* W_pos1 = (const float*)d_in[5];
    const float* b_pos1 = (const float*)d_in[6];
    const float* W_neg1 = (const float*)d_in[7];
    const float* b_neg1 = (const float*)d_in[8];
    const float* W_reg = (const float*)d_in[9];
    const int* pe = (const int*)d_in[10];
    const int* ne = (const int*)d_in[11];
    const int* target = (const int*)d_in[12];
    const int* ps = (const int*)d_in[13];
    const int* ns = (const int*)d_in[14];
    float* out = (float*)d_out;
    float* ws = (float*)d_ws;
    int* wsi = (int*)d_ws;

    float* acc = ws + ACC_OFF;
    int* cntP = wsi + I_CNTP;
    int* cntN = wsi + I_CNTN;
    int* curP = wsi + I_CURP;
    int* curN = wsi + I_CURN;
    int* offP = wsi + I_OFFP;
    int* offN = wsi + I_OFFN;
    int* csrP = wsi + I_CSRP;
    int* csrN = wsi + I_CSRN;
    float* h_pos = ws + F_BUF;
    float* h_neg = h_pos + BUF_SZ;
    float* z = out + 1;

    // zero acc + counts + cursors (contiguous region)
    hipMemsetAsync(ws, 0, (size_t)(16 + 4 * N_NODES) * sizeof(float), stream);

    count_kernel<<<(EP_N + EN_N + 255) / 256, 256, 0, stream>>>(pe, ne, cntP, cntN);
    scan_kernel<<<2, 1024, 0, stream>>>(cntP, cntN, offP, offN);
    fill_kernel<<<(EP_N + EN_N + 255) / 256, 256, 0, stream>>>(pe, ne, offP, offN,
                                                               curP, curN, csrP, csrN);

    base_fused<<<NODE_BLOCKS, 256, 0, stream>>>(X, offP, csrP, W_pos0, b_pos0, h_pos);
    base_fused<<<NODE_BLOCKS, 256, 0, stream>>>(X, offN, csrN, W_neg0, b_neg0, h_neg);

    deep_fused<<<NODE_BLOCKS, 256, 0, stream>>>(h_pos, h_neg, offP, csrP, offN, csrN,
                                                W_pos1, b_pos1, z, 0);
    deep_fused<<<NODE_BLOCKS, 256, 0, stream>>>(h_neg, h_pos, offP, csrP, offN, csrN,
                                                W_neg1, b_neg1, z, 32);

    loss_kernel<<<1024, 256, 0, stream>>>(z, pe, ne, ps, ns, target, W_reg, acc);
    finalize_kernel<<<1, 1, 0, stream>>>(acc, out);
}

// Round 3
// 691.860 us; speedup vs baseline: 2.5398x; 1.5718x over previous
//
#include <hip/hip_runtime.h>
#include <cstdint>

#define N_NODES 100000
#define EP_N 400000
#define EN_N 400000
#define NODE_BLOCKS ((N_NODES + 63) / 64)

// ws layout (in 4-byte units)
#define ACC_OFF 0                      // 16 floats
#define I_CNTP 16
#define I_CNTN (I_CNTP + N_NODES)
#define I_CURP (I_CNTN + N_NODES)
#define I_CURN (I_CURP + N_NODES)
#define I_OFFP (I_CURN + N_NODES)
#define I_OFFN (I_OFFP + N_NODES + 1)
#define I_CSRP (I_OFFN + N_NODES + 1)
#define I_CSRN (I_CSRP + EP_N)
#define F_BUF (((I_CSRN + EN_N) + 15) & ~15)
#define BUF_SZ (64 * N_NODES)
#define F_PN (F_BUF + 2 * BUF_SZ)          // pn: N*8 floats
#define F_ZB (F_PN + 8 * N_NODES)          // zb: N*64 ushort (N*32 float slots)

__device__ inline float bf2f(unsigned short u) {
    return __uint_as_float((unsigned)u << 16);
}

__global__ void count_kernel(const int* __restrict__ pe, const int* __restrict__ ne,
                             int* cp, int* cn) {
    int i = blockIdx.x * 256 + threadIdx.x;
    if (i < EP_N) {
        atomicAdd(&cp[pe[i]], 1);
    } else if (i < EP_N + EN_N) {
        atomicAdd(&cn[ne[i - EP_N]], 1);
    }
}

__global__ __launch_bounds__(1024) void scan_kernel(const int* __restrict__ cntP,
                                                    const int* __restrict__ cntN,
                                                    int* offP, int* offN) {
    const int* cnt = blockIdx.x == 0 ? cntP : cntN;
    int* off = blockIdx.x == 0 ? offP : offN;
    const int n = N_NODES;
    const int chunk = (n + 1023) / 1024;
    int t = threadIdx.x;
    int beg = t * chunk;
    int end = beg + chunk < n ? beg + chunk : n;
    int s = 0;
    for (int i = beg; i < end; ++i) s += cnt[i];
    __shared__ int tmp[1024];
    tmp[t] = s;
    __syncthreads();
    for (int d = 1; d < 1024; d <<= 1) {
        int v = (t >= d) ? tmp[t - d] : 0;
        __syncthreads();
        tmp[t] += v;
        __syncthreads();
    }
    int running = tmp[t] - s;
    for (int i = beg; i < end; ++i) {
        off[i] = running;
        running += cnt[i];
    }
    if (beg < n && end == n) off[n] = running;
}

__global__ void fill_kernel(const int* __restrict__ pe, const int* __restrict__ ne,
                            const int* __restrict__ offP, const int* __restrict__ offN,
                            int* curP, int* curN, int* csrP, int* csrN) {
    int e = blockIdx.x * 256 + threadIdx.x;
    if (e < EP_N) {
        int row = pe[e], col = pe[EP_N + e];
        int slot = atomicAdd(&curP[row], 1);
        csrP[offP[row] + slot] = col;
    } else if (e < EP_N + EN_N) {
        int e2 = e - EP_N;
        int row = ne[e2], col = ne[EN_N + e2];
        int slot = atomicAdd(&curN[row], 1);
        csrN[offN[row] + slot] = col;
    }
}

// masked 4-unroll gather-mean of src rows listed in csr[st..en) -> per-lane sum
__device__ inline float gather_mean(const float* __restrict__ src,
                                    const int* __restrict__ csr,
                                    int st, int en, int lane) {
    float s0 = 0.f, s1 = 0.f, s2 = 0.f, s3 = 0.f;
    for (int p = st; p < en; p += 4) {
        int c0 = csr[p];
        int c1 = csr[min(p + 1, en - 1)];
        int c2 = csr[min(p + 2, en - 1)];
        int c3 = csr[min(p + 3, en - 1)];
        float v0 = src[(long long)c0 * 64 + lane];
        float v1 = src[(long long)c1 * 64 + lane];
        float v2 = src[(long long)c2 * 64 + lane];
        float v3 = src[(long long)c3 * 64 + lane];
        s0 += v0;
        s1 += (p + 1 < en) ? v1 : 0.f;
        s2 += (p + 2 < en) ? v2 : 0.f;
        s3 += (p + 3 < en) ? v3 : 0.f;
    }
    return ((s0 + s1) + (s2 + s3)) / fmaxf((float)(en - st), 1.0f);
}

// h = tanh([gather_mean(X, csr), X] @ W + b); block = 64 nodes, 512 threads.
__global__ __launch_bounds__(512) void base_fused(
    const float* __restrict__ X, const int* __restrict__ off,
    const int* __restrict__ csr, const float* __restrict__ W,
    const float* __restrict__ b, float* __restrict__ out) {
    __shared__ float in_lds[64 * 129];
    int tid = threadIdx.x, lane = tid & 63, w = tid >> 6;
    int base = blockIdx.x * 64;
    for (int r = w * 8; r < w * 8 + 8; ++r) {
        int node = base + r;
        float selfv = 0.f, sum = 0.f;
        if (node < N_NODES) {
            selfv = X[(long long)node * 64 + lane];
            int st = off[node], en = off[node + 1];
            sum = gather_mean(X, csr, st, en, lane);
        }
        in_lds[r * 129 + lane] = sum;
        in_lds[r * 129 + 64 + lane] = selfv;
    }
    __syncthreads();
    int wu = __builtin_amdgcn_readfirstlane(w);
    const float* Wp = W + wu * 8;
    const float* bp = b + wu * 8;
    float acc[8];
#pragma unroll
    for (int j = 0; j < 8; ++j) acc[j] = 0.f;
    const float* row = &in_lds[lane * 129];
    for (int k = 0; k < 128; ++k) {
        float v = row[k];
#pragma unroll
        for (int j = 0; j < 8; ++j) acc[j] = fmaf(v, Wp[k * 64 + j], acc[j]);
    }
#pragma unroll
    for (int j = 0; j < 8; ++j) acc[j] = tanhf(acc[j] + bp[j]);
    __syncthreads();
    float* ot = in_lds;  // 64 x 65
#pragma unroll
    for (int j = 0; j < 8; ++j) ot[lane * 65 + wu * 8 + j] = acc[j];
    __syncthreads();
    for (int i = tid; i < 64 * 64; i += 512) {
        int r = i >> 6, c = i & 63;
        int node = base + r;
        if (node < N_NODES) out[(long long)node * 64 + c] = ot[r * 65 + c];
    }
}

// zcols = tanh([gm(f1,csrP), gm(f2,csrN), f1] @ W + b); 32 cols at colOff
__global__ __launch_bounds__(512) void deep_fused(
    const float* __restrict__ f1, const float* __restrict__ f2,
    const int* __restrict__ offP, const int* __restrict__ csrP,
    const int* __restrict__ offN, const int* __restrict__ csrN,
    const float* __restrict__ W, const float* __restrict__ b,
    float* __restrict__ zout, int colOff) {
    __shared__ float in_lds[64 * 193];
    int tid = threadIdx.x, lane = tid & 63, w = tid >> 6;
    int base = blockIdx.x * 64;
    for (int r = w * 8; r < w * 8 + 8; ++r) {
        int node = base + r;
        float g1 = 0.f, g2 = 0.f, selfv = 0.f;
        if (node < N_NODES) {
            g1 = gather_mean(f1, csrP, offP[node], offP[node + 1], lane);
            g2 = gather_mean(f2, csrN, offN[node], offN[node + 1], lane);
            selfv = f1[(long long)node * 64 + lane];
        }
        in_lds[r * 193 + lane] = g1;
        in_lds[r * 193 + 64 + lane] = g2;
        in_lds[r * 193 + 128 + lane] = selfv;
    }
    __syncthreads();
    int wu = __builtin_amdgcn_readfirstlane(w);
    const float* Wp = W + wu * 4;
    const float* bp = b + wu * 4;
    float acc[4];
#pragma unroll
    for (int j = 0; j < 4; ++j) acc[j] = 0.f;
    const float* row = &in_lds[lane * 193];
    for (int k = 0; k < 192; ++k) {
        float v = row[k];
#pragma unroll
        for (int j = 0; j < 4; ++j) acc[j] = fmaf(v, Wp[k * 32 + j], acc[j]);
    }
#pragma unroll
    for (int j = 0; j < 4; ++j) acc[j] = tanhf(acc[j] + bp[j]);
    __syncthreads();
    float* ot = in_lds;  // 64 x 33
#pragma unroll
    for (int j = 0; j < 4; ++j) ot[lane * 33 + wu * 4 + j] = acc[j];
    __syncthreads();
    for (int i = tid; i < 64 * 32; i += 512) {
        int r = i >> 5, c = i & 31;
        int node = base + r;
        if (node < N_NODES) zout[(long long)node * 64 + colOff + c] = ot[r * 33 + c];
    }
}

// per-node: bf16 copy of z + {u0,u1,v0,v1,||z||^2} projections (from bf16 values)
__global__ __launch_bounds__(256) void node_proj(
    const float* __restrict__ z, const float* __restrict__ Wreg,
    unsigned short* __restrict__ zb, float* __restrict__ pn) {
    int tid = threadIdx.x, lane = tid & 63, w = tid >> 6;
    int node = blockIdx.x * 4 + w;
    if (node >= N_NODES) return;
    float v = z[(long long)node * 64 + lane];
    unsigned u = __float_as_uint(v);
    unsigned r = (u + 0x7FFFu + ((u >> 16) & 1u)) >> 16;
    zb[(long long)node * 64 + lane] = (unsigned short)r;
    float vb = __uint_as_float(r << 16);
    float u0 = vb * Wreg[lane * 2 + 0];
    float u1 = vb * Wreg[lane * 2 + 1];
    float v0 = vb * Wreg[(64 + lane) * 2 + 0];
    float v1 = vb * Wreg[(64 + lane) * 2 + 1];
    float s = vb * vb;
#pragma unroll
    for (int off = 32; off; off >>= 1) {
        u0 += __shfl_xor(u0, off);
        u1 += __shfl_xor(u1, off);
        v0 += __shfl_xor(v0, off);
        v1 += __shfl_xor(v1, off);
        s += __shfl_xor(s, off);
    }
    if (lane == 0) {
        float* p = pn + (long long)node * 8;
        p[0] = u0; p[1] = u1; p[2] = v0; p[3] = v1; p[4] = s;
    }
}

// 4 edges per wave (16-lane groups): cross-dots + precomputed node scalars
__global__ __launch_bounds__(256) void loss2_kernel(
    const unsigned short* __restrict__ zb, const float* __restrict__ pn,
    const int* __restrict__ pe, const int* __restrict__ ne,
    const int* __restrict__ ps, const int* __restrict__ ns,
    const int* __restrict__ tgt, float* acc) {
    int tid = threadIdx.x;
    int lane = tid & 63;
    int g = lane >> 4, sub = lane & 15;
    int wid = (blockIdx.x * 256 + tid) >> 6;
    int nw = (gridDim.x * 256) >> 6;
    float s_p = 0.f, s_n = 0.f, s_r = 0.f;
    const float q = 0.0625f;
    for (int eb = wid * 4; eb < EP_N + EN_N; eb += nw * 4) {
        int e = eb + g;
        bool valid = e < EP_N + EN_N;
        bool isp = e < EP_N;
        int i = 0, j = 0, k = 0, t = 0;
        if (valid) {
            if (isp) {
                i = pe[e]; j = pe[EP_N + e]; k = ps[e];
            } else {
                int e2 = e - EP_N;
                i = ne[e2]; j = ne[EN_N + e2]; k = ns[e2];
            }
            t = tgt[e];
        }
        const ushort4 zi4 = *(const ushort4*)(zb + ((long long)i << 6) + (sub << 2));
        const ushort4 zj4 = *(const ushort4*)(zb + ((long long)j << 6) + (sub << 2));
        const ushort4 zk4 = *(const ushort4*)(zb + ((long long)k << 6) + (sub << 2));
        float zi0 = bf2f(zi4.x), zi1 = bf2f(zi4.y), zi2 = bf2f(zi4.z), zi3 = bf2f(zi4.w);
        float zj0 = bf2f(zj4.x), zj1 = bf2f(zj4.y), zj2 = bf2f(zj4.z), zj3 = bf2f(zj4.w);
        float zk0 = bf2f(zk4.x), zk1 = bf2f(zk4.y), zk2 = bf2f(zk4.z), zk3 = bf2f(zk4.w);
        float d1 = zi0 * zj0 + zi1 * zj1 + zi2 * zj2 + zi3 * zj3;
        float d2 = zj0 * zk0 + zj1 * zk1 + zj2 * zk2 + zj3 * zk3;
#pragma unroll
        for (int off = 1; off < 16; off <<= 1) {
            d1 += __shfl_xor(d1, off);
            d2 += __shfl_xor(d2, off);
        }
        if (valid) {
            const float* pni = pn + ((long long)i << 3);
            const float* pnj = pn + ((long long)j << 3);
            float u0 = pni[0], u1 = pni[1], si = pni[4];
            float v0 = pnj[2], v1 = pnj[3], sj = pnj[4];
            float sk = pn[((long long)k << 3) + 4];
            float nij = si + sj - 2.f * d1;
            float nik = sj + sk - 2.f * d2;
            float tri = fmaxf(nij - nik, 0.f);
            float l0 = u0 + v0, l1 = u1 + v1;
            float m = fmaxf(l0, l1);
            float lse = m + logf(expf(l0 - m) + expf(l1 - m));
            float r = lse - (t ? l1 : l0);
            s_r += r * q;
            if (isp) s_p += tri * q; else s_n += tri * q;
        }
    }
#pragma unroll
    for (int off = 32; off; off >>= 1) {
        s_p += __shfl_xor(s_p, off);
        s_n += __shfl_xor(s_n, off);
        s_r += __shfl_xor(s_r, off);
    }
    __shared__ float red[3][4];
    int w = tid >> 6;
    if (lane == 0) {
        red[0][w] = s_p; red[1][w] = s_n; red[2][w] = s_r;
    }
    __syncthreads();
    if (tid == 0) {
        atomicAdd(&acc[0], red[0][0] + red[0][1] + red[0][2] + red[0][3]);
        atomicAdd(&acc[1], red[1][0] + red[1][1] + red[1][2] + red[1][3]);
        atomicAdd(&acc[2], red[2][0] + red[2][1] + red[2][2] + red[2][3]);
    }
}

__global__ void finalize_kernel(const float* __restrict__ acc, float* out) {
    out[0] = acc[2] / (float)(EP_N + EN_N) +
             1.0f * (acc[0] / (float)EP_N + acc[1] / (float)EN_N);
}

extern "C" void kernel_launch(void* const* d_in, const int* in_sizes, int n_in,
                              void* d_out, int out_size, void* d_ws, size_t ws_size,
                              hipStream_t stream) {
    const float* X = (const float*)d_in[0];
    const float* W_pos0 = (const float*)d_in[1];
    const float* b_pos0 = (const float*)d_in[2];
    const float* W_neg0 = (const float*)d_in[3];
    const float* b_neg0 = (const float*)d_in[4];
    const float* W_pos1 = (const float*)d_in[5];
    const float* b_pos1 = (const float*)d_in[6];
    const float* W_neg1 = (const float*)d_in[7];
    const float* b_neg1 = (const float*)d_in[8];
    const float* W_reg = (const float*)d_in[9];
    const int* pe = (const int*)d_in[10];
    const int* ne = (const int*)d_in[11];
    const int* target = (const int*)d_in[12];
    const int* ps = (const int*)d_in[13];
    const int* ns = (const int*)d_in[14];
    float* out = (float*)d_out;
    float* ws = (float*)d_ws;
    int* wsi = (int*)d_ws;

    float* acc = ws + ACC_OFF;
    int* cntP = wsi + I_CNTP;
    int* cntN = wsi + I_CNTN;
    int* curP = wsi + I_CURP;
    int* curN = wsi + I_CURN;
    int* offP = wsi + I_OFFP;
    int* offN = wsi + I_OFFN;
    int* csrP = wsi + I_CSRP;
    int* csrN = wsi + I_CSRN;
    float* h_pos = ws + F_BUF;
    float* h_neg = h_pos + BUF_SZ;
    float* pn = ws + F_PN;
    unsigned short* zb = (unsigned short*)(ws + F_ZB);
    float* z = out + 1;

    hipMemsetAsync(ws, 0, (size_t)(16 + 4 * N_NODES) * sizeof(float), stream);

    count_kernel<<<(EP_N + EN_N + 255) / 256, 256, 0, stream>>>(pe, ne, cntP, cntN);
    scan_kernel<<<2, 1024, 0, stream>>>(cntP, cntN, offP, offN);
    fill_kernel<<<(EP_N + EN_N + 255) / 256, 256, 0, stream>>>(pe, ne, offP, offN,
                                                               curP, curN, csrP, csrN);

    base_fused<<<NODE_BLOCKS, 512, 0, stream>>>(X, offP, csrP, W_pos0, b_pos0, h_pos);
    base_fused<<<NODE_BLOCKS, 512, 0, stream>>>(X, offN, csrN, W_neg0, b_neg0, h_neg);

    deep_fused<<<NODE_BLOCKS, 512, 0, stream>>>(h_pos, h_neg, offP, csrP, offN, csrN,
                                                W_pos1, b_pos1, z, 0);
    deep_fused<<<NODE_BLOCKS, 512, 0, stream>>>(h_neg, h_pos, offP, csrP, offN, csrN,
                                                W_neg1, b_neg1, z, 32);

    node_proj<<<(N_NODES + 3) / 4, 256, 0, stream>>>(z, W_reg, zb, pn);
    loss2_kernel<<<1024, 256, 0, stream>>>(zb, pn, pe, ne, ps, ns, target, acc);
    finalize_kernel<<<1, 1, 0, stream>>>(acc, out);
}

// Round 4
// 534.682 us; speedup vs baseline: 3.2864x; 1.2940x over previous
//
#include <hip/hip_runtime.h>
#include <cstdint>

#define N_NODES 100000
#define EP_N 400000
#define EN_N 400000
#define NODE_BLOCKS ((N_NODES + 63) / 64)
#define SCHUNK 512
#define SBLK ((N_NODES + SCHUNK - 1) / SCHUNK)   // 196 blocks per list

// ws layout (in 4-byte units)
#define ACC_OFF 0                      // 16 floats
#define I_CNTP 16
#define I_CNTN (I_CNTP + N_NODES)
#define I_CURP (I_CNTN + N_NODES)
#define I_CURN (I_CURP + N_NODES)
#define I_OFFP (I_CURN + N_NODES)
#define I_OFFN (I_OFFP + N_NODES + 1)
#define I_CSRP (I_OFFN + N_NODES + 1)
#define I_CSRN (I_CSRP + EP_N)
#define I_PART (I_CSRN + EN_N)
#define F_BUF (((I_PART + 2 * SBLK) + 15) & ~15)
#define H_SLOTS (32 * N_NODES)         // bf16 h array: 64*N ushorts = 32*N float slots
#define F_PN (F_BUF + 2 * H_SLOTS)     // pn: N*8 floats
#define F_ZB (F_PN + 8 * N_NODES)      // zb: N*64 ushort

__device__ inline float bf2f(unsigned short u) {
    return __uint_as_float((unsigned)u << 16);
}
__device__ inline unsigned short f2bf(float v) {
    unsigned u = __float_as_uint(v);
    return (unsigned short)((u + 0x7FFFu + ((u >> 16) & 1u)) >> 16);
}

__global__ void count_kernel(const int* __restrict__ pe, const int* __restrict__ ne,
                             int* cp, int* cn) {
    int i = blockIdx.x * 256 + threadIdx.x;
    if (i < EP_N) {
        atomicAdd(&cp[pe[i]], 1);
    } else if (i < EP_N + EN_N) {
        atomicAdd(&cn[ne[i - EP_N]], 1);
    }
}

// phase 1: per-block partial sums of counts
__global__ __launch_bounds__(512) void scan_p1(const int* __restrict__ cntP,
                                               const int* __restrict__ cntN,
                                               int* part) {
    int l = blockIdx.x < SBLK ? 0 : 1;
    int blk = blockIdx.x - l * SBLK;
    const int* cnt = l == 0 ? cntP : cntN;
    int idx = blk * SCHUNK + threadIdx.x;
    int v = idx < N_NODES ? cnt[idx] : 0;
    __shared__ int tmp[512];
    tmp[threadIdx.x] = v;
    __syncthreads();
    for (int d = 256; d > 0; d >>= 1) {
        if (threadIdx.x < d) tmp[threadIdx.x] += tmp[threadIdx.x + d];
        __syncthreads();
    }
    if (threadIdx.x == 0) part[l * SBLK + blk] = tmp[0];
}

// phase 2: one block scans both partial arrays (exclusive), in place
__global__ __launch_bounds__(512) void scan_p2(int* part) {
    int t = threadIdx.x;
    int l = t >> 8, idx = t & 255;            // 256-wide segment per list
    int v = idx < SBLK ? part[l * SBLK + idx] : 0;
    __shared__ int tmp[512];
    int sb = l << 8;
    tmp[sb + idx] = v;
    __syncthreads();
    for (int d = 1; d < 256; d <<= 1) {
        int x = (idx >= d) ? tmp[sb + idx - d] : 0;
        __syncthreads();
        tmp[sb + idx] += x;
        __syncthreads();
    }
    if (idx < SBLK) part[l * SBLK + idx] = tmp[sb + idx] - v;  // exclusive
}

// phase 3: per-block local scan + base -> offsets
__global__ __launch_bounds__(512) void scan_p3(const int* __restrict__ cntP,
                                               const int* __restrict__ cntN,
                                               const int* __restrict__ part,
                                               int* offP, int* offN) {
    int l = blockIdx.x < SBLK ? 0 : 1;
    int blk = blockIdx.x - l * SBLK;
    const int* cnt = l == 0 ? cntP : cntN;
    int* off = l == 0 ? offP : offN;
    int base = part[l * SBLK + blk];
    int t = threadIdx.x;
    int gidx = blk * SCHUNK + t;
    int c = gidx < N_NODES ? cnt[gidx] : 0;
    __shared__ int tmp[512];
    tmp[t] = c;
    __syncthreads();
    for (int d = 1; d < 512; d <<= 1) {
        int x = (t >= d) ? tmp[t - d] : 0;
        __syncthreads();
        tmp[t] += x;
        __syncthreads();
    }
    int incl = tmp[t];
    if (gidx < N_NODES) off[gidx] = base + incl - c;
    if (gidx == N_NODES - 1) off[N_NODES] = base + incl;
}

__global__ void fill_kernel(const int* __restrict__ pe, const int* __restrict__ ne,
                            const int* __restrict__ offP, const int* __restrict__ offN,
                            int* curP, int* curN, int* csrP, int* csrN) {
    int e = blockIdx.x * 256 + threadIdx.x;
    if (e < EP_N) {
        int row = pe[e], col = pe[EP_N + e];
        int slot = atomicAdd(&curP[row], 1);
        csrP[offP[row] + slot] = col;
    } else if (e < EP_N + EN_N) {
        int e2 = e - EP_N;
        int row = ne[e2], col = ne[EN_N + e2];
        int slot = atomicAdd(&curN[row], 1);
        csrN[offN[row] + slot] = col;
    }
}

// masked 4-unroll gather-mean (f32 rows)
__device__ inline float gather_mean(const float* __restrict__ src,
                                    const int* __restrict__ csr,
                                    int st, int en, int lane) {
    float s0 = 0.f, s1 = 0.f, s2 = 0.f, s3 = 0.f;
    for (int p = st; p < en; p += 4) {
        int c0 = csr[p];
        int c1 = csr[min(p + 1, en - 1)];
        int c2 = csr[min(p + 2, en - 1)];
        int c3 = csr[min(p + 3, en - 1)];
        float v0 = src[(long long)c0 * 64 + lane];
        float v1 = src[(long long)c1 * 64 + lane];
        float v2 = src[(long long)c2 * 64 + lane];
        float v3 = src[(long long)c3 * 64 + lane];
        s0 += v0;
        s1 += (p + 1 < en) ? v1 : 0.f;
        s2 += (p + 2 < en) ? v2 : 0.f;
        s3 += (p + 3 < en) ? v3 : 0.f;
    }
    return ((s0 + s1) + (s2 + s3)) / fmaxf((float)(en - st), 1.0f);
}

// masked 4-unroll gather-mean (bf16 rows)
__device__ inline float gather_mean_h(const unsigned short* __restrict__ src,
                                      const int* __restrict__ csr,
                                      int st, int en, int lane) {
    float s0 = 0.f, s1 = 0.f, s2 = 0.f, s3 = 0.f;
    for (int p = st; p < en; p += 4) {
        int c0 = csr[p];
        int c1 = csr[min(p + 1, en - 1)];
        int c2 = csr[min(p + 2, en - 1)];
        int c3 = csr[min(p + 3, en - 1)];
        float v0 = bf2f(src[(long long)c0 * 64 + lane]);
        float v1 = bf2f(src[(long long)c1 * 64 + lane]);
        float v2 = bf2f(src[(long long)c2 * 64 + lane]);
        float v3 = bf2f(src[(long long)c3 * 64 + lane]);
        s0 += v0;
        s1 += (p + 1 < en) ? v1 : 0.f;
        s2 += (p + 2 < en) ? v2 : 0.f;
        s3 += (p + 3 < en) ? v3 : 0.f;
    }
    return ((s0 + s1) + (s2 + s3)) / fmaxf((float)(en - st), 1.0f);
}

// h = tanh([gather_mean(X, csr), X] @ W + b) -> bf16; block = 64 nodes, 512 threads.
__global__ __launch_bounds__(512) void base_fused(
    const float* __restrict__ X, const int* __restrict__ off,
    const int* __restrict__ csr, const float* __restrict__ W,
    const float* __restrict__ b, unsigned short* __restrict__ out) {
    __shared__ float in_lds[64 * 129];
    int tid = threadIdx.x, lane = tid & 63, w = tid >> 6;
    int base = blockIdx.x * 64;
    for (int r = w * 8; r < w * 8 + 8; ++r) {
        int node = base + r;
        float selfv = 0.f, sum = 0.f;
        if (node < N_NODES) {
            selfv = X[(long long)node * 64 + lane];
            int st = off[node], en = off[node + 1];
            sum = gather_mean(X, csr, st, en, lane);
        }
        in_lds[r * 129 + lane] = sum;
        in_lds[r * 129 + 64 + lane] = selfv;
    }
    __syncthreads();
    int wu = __builtin_amdgcn_readfirstlane(w);
    const float* Wp = W + wu * 8;
    const float* bp = b + wu * 8;
    float acc[8];
#pragma unroll
    for (int j = 0; j < 8; ++j) acc[j] = 0.f;
    const float* row = &in_lds[lane * 129];
    for (int k = 0; k < 128; ++k) {
        float v = row[k];
#pragma unroll
        for (int j = 0; j < 8; ++j) acc[j] = fmaf(v, Wp[k * 64 + j], acc[j]);
    }
#pragma unroll
    for (int j = 0; j < 8; ++j) acc[j] = tanhf(acc[j] + bp[j]);
    __syncthreads();
    float* ot = in_lds;  // 64 x 65
#pragma unroll
    for (int j = 0; j < 8; ++j) ot[lane * 65 + wu * 8 + j] = acc[j];
    __syncthreads();
    for (int i = tid; i < 64 * 64; i += 512) {
        int r = i >> 6, c = i & 63;
        int node = base + r;
        if (node < N_NODES) out[(long long)node * 64 + c] = f2bf(ot[r * 65 + c]);
    }
}

// zcols = tanh([gm(f1,csrP), gm(f2,csrN), f1] @ W + b); 32 cols at colOff; f* are bf16
__global__ __launch_bounds__(512) void deep_fused(
    const unsigned short* __restrict__ f1, const unsigned short* __restrict__ f2,
    const int* __restrict__ offP, const int* __restrict__ csrP,
    const int* __restrict__ offN, const int* __restrict__ csrN,
    const float* __restrict__ W, const float* __restrict__ b,
    float* __restrict__ zout, int colOff) {
    __shared__ float in_lds[64 * 193];
    int tid = threadIdx.x, lane = tid & 63, w = tid >> 6;
    int base = blockIdx.x * 64;
    for (int r = w * 8; r < w * 8 + 8; ++r) {
        int node = base + r;
        float g1 = 0.f, g2 = 0.f, selfv = 0.f;
        if (node < N_NODES) {
            g1 = gather_mean_h(f1, csrP, offP[node], offP[node + 1], lane);
            g2 = gather_mean_h(f2, csrN, offN[node], offN[node + 1], lane);
            selfv = bf2f(f1[(long long)node * 64 + lane]);
        }
        in_lds[r * 193 + lane] = g1;
        in_lds[r * 193 + 64 + lane] = g2;
        in_lds[r * 193 + 128 + lane] = selfv;
    }
    __syncthreads();
    int wu = __builtin_amdgcn_readfirstlane(w);
    const float* Wp = W + wu * 4;
    const float* bp = b + wu * 4;
    float acc[4];
#pragma unroll
    for (int j = 0; j < 4; ++j) acc[j] = 0.f;
    const float* row = &in_lds[lane * 193];
    for (int k = 0; k < 192; ++k) {
        float v = row[k];
#pragma unroll
        for (int j = 0; j < 4; ++j) acc[j] = fmaf(v, Wp[k * 32 + j], acc[j]);
    }
#pragma unroll
    for (int j = 0; j < 4; ++j) acc[j] = tanhf(acc[j] + bp[j]);
    __syncthreads();
    float* ot = in_lds;  // 64 x 33
#pragma unroll
    for (int j = 0; j < 4; ++j) ot[lane * 33 + wu * 4 + j] = acc[j];
    __syncthreads();
    for (int i = tid; i < 64 * 32; i += 512) {
        int r = i >> 5, c = i & 31;
        int node = base + r;
        if (node < N_NODES) zout[(long long)node * 64 + colOff + c] = ot[r * 33 + c];
    }
}

// per-node: bf16 copy of z + {u0,u1,v0,v1,||z||^2} projections (from bf16 values)
__global__ __launch_bounds__(256) void node_proj(
    const float* __restrict__ z, const float* __restrict__ Wreg,
    unsigned short* __restrict__ zb, float* __restrict__ pn) {
    int tid = threadIdx.x, lane = tid & 63, w = tid >> 6;
    int node = blockIdx.x * 4 + w;
    if (node >= N_NODES) return;
    float v = z[(long long)node * 64 + lane];
    unsigned short r = f2bf(v);
    zb[(long long)node * 64 + lane] = r;
    float vb = bf2f(r);
    float u0 = vb * Wreg[lane * 2 + 0];
    float u1 = vb * Wreg[lane * 2 + 1];
    float v0 = vb * Wreg[(64 + lane) * 2 + 0];
    float v1 = vb * Wreg[(64 + lane) * 2 + 1];
    float s = vb * vb;
#pragma unroll
    for (int off = 32; off; off >>= 1) {
        u0 += __shfl_xor(u0, off);
        u1 += __shfl_xor(u1, off);
        v0 += __shfl_xor(v0, off);
        v1 += __shfl_xor(v1, off);
        s += __shfl_xor(s, off);
    }
    if (lane == 0) {
        float* p = pn + (long long)node * 8;
        p[0] = u0; p[1] = u1; p[2] = v0; p[3] = v1; p[4] = s;
    }
}

// 4 edges per wave (16-lane groups): cross-dots + precomputed node scalars
__global__ __launch_bounds__(256) void loss2_kernel(
    const unsigned short* __restrict__ zb, const float* __restrict__ pn,
    const int* __restrict__ pe, const int* __restrict__ ne,
    const int* __restrict__ ps, const int* __restrict__ ns,
    const int* __restrict__ tgt, float* acc) {
    int tid = threadIdx.x;
    int lane = tid & 63;
    int g = lane >> 4, sub = lane & 15;
    int wid = (blockIdx.x * 256 + tid) >> 6;
    int nw = (gridDim.x * 256) >> 6;
    float s_p = 0.f, s_n = 0.f, s_r = 0.f;
    const float q = 0.0625f;
    for (int eb = wid * 4; eb < EP_N + EN_N; eb += nw * 4) {
        int e = eb + g;
        bool valid = e < EP_N + EN_N;
        bool isp = e < EP_N;
        int i = 0, j = 0, k = 0, t = 0;
        if (valid) {
            if (isp) {
                i = pe[e]; j = pe[EP_N + e]; k = ps[e];
            } else {
                int e2 = e - EP_N;
                i = ne[e2]; j = ne[EN_N + e2]; k = ns[e2];
            }
            t = tgt[e];
        }
        const ushort4 zi4 = *(const ushort4*)(zb + ((long long)i << 6) + (sub << 2));
        const ushort4 zj4 = *(const ushort4*)(zb + ((long long)j << 6) + (sub << 2));
        const ushort4 zk4 = *(const ushort4*)(zb + ((long long)k << 6) + (sub << 2));
        float zi0 = bf2f(zi4.x), zi1 = bf2f(zi4.y), zi2 = bf2f(zi4.z), zi3 = bf2f(zi4.w);
        float zj0 = bf2f(zj4.x), zj1 = bf2f(zj4.y), zj2 = bf2f(zj4.z), zj3 = bf2f(zj4.w);
        float zk0 = bf2f(zk4.x), zk1 = bf2f(zk4.y), zk2 = bf2f(zk4.z), zk3 = bf2f(zk4.w);
        float d1 = zi0 * zj0 + zi1 * zj1 + zi2 * zj2 + zi3 * zj3;
        float d2 = zj0 * zk0 + zj1 * zk1 + zj2 * zk2 + zj3 * zk3;
#pragma unroll
        for (int off = 1; off < 16; off <<= 1) {
            d1 += __shfl_xor(d1, off);
            d2 += __shfl_xor(d2, off);
        }
        if (valid) {
            const float* pni = pn + ((long long)i << 3);
            const float* pnj = pn + ((long long)j << 3);
            float u0 = pni[0], u1 = pni[1], si = pni[4];
            float v0 = pnj[2], v1 = pnj[3], sj = pnj[4];
            float sk = pn[((long long)k << 3) + 4];
            float nij = si + sj - 2.f * d1;
            float nik = sj + sk - 2.f * d2;
            float tri = fmaxf(nij - nik, 0.f);
            float l0 = u0 + v0, l1 = u1 + v1;
            float m = fmaxf(l0, l1);
            float lse = m + logf(expf(l0 - m) + expf(l1 - m));
            float r = lse - (t ? l1 : l0);
            s_r += r * q;
            if (isp) s_p += tri * q; else s_n += tri * q;
        }
    }
#pragma unroll
    for (int off = 32; off; off >>= 1) {
        s_p += __shfl_xor(s_p, off);
        s_n += __shfl_xor(s_n, off);
        s_r += __shfl_xor(s_r, off);
    }
    __shared__ float red[3][4];
    int w = tid >> 6;
    if (lane == 0) {
        red[0][w] = s_p; red[1][w] = s_n; red[2][w] = s_r;
    }
    __syncthreads();
    if (tid == 0) {
        atomicAdd(&acc[0], red[0][0] + red[0][1] + red[0][2] + red[0][3]);
        atomicAdd(&acc[1], red[1][0] + red[1][1] + red[1][2] + red[1][3]);
        atomicAdd(&acc[2], red[2][0] + red[2][1] + red[2][2] + red[2][3]);
    }
}

__global__ void finalize_kernel(const float* __restrict__ acc, float* out) {
    out[0] = acc[2] / (float)(EP_N + EN_N) +
             1.0f * (acc[0] / (float)EP_N + acc[1] / (float)EN_N);
}

extern "C" void kernel_launch(void* const* d_in, const int* in_sizes, int n_in,
                              void* d_out, int out_size, void* d_ws, size_t ws_size,
                              hipStream_t stream) {
    const float* X = (const float*)d_in[0];
    const float* W_pos0 = (const float*)d_in[1];
    const float* b_pos0 = (const float*)d_in[2];
    const float* W_neg0 = (const float*)d_in[3];
    const float* b_neg0 = (const float*)d_in[4];
    const float* W_pos1 = (const float*)d_in[5];
    const float* b_pos1 = (const float*)d_in[6];
    const float* W_neg1 = (const float*)d_in[7];
    const float* b_neg1 = (const float*)d_in[8];
    const float* W_reg = (const float*)d_in[9];
    const int* pe = (const int*)d_in[10];
    const int* ne = (const int*)d_in[11];
    const int* target = (const int*)d_in[12];
    const int* ps = (const int*)d_in[13];
    const int* ns = (const int*)d_in[14];
    float* out = (float*)d_out;
    float* ws = (float*)d_ws;
    int* wsi = (int*)d_ws;

    float* acc = ws + ACC_OFF;
    int* cntP = wsi + I_CNTP;
    int* cntN = wsi + I_CNTN;
    int* curP = wsi + I_CURP;
    int* curN = wsi + I_CURN;
    int* offP = wsi + I_OFFP;
    int* offN = wsi + I_OFFN;
    int* csrP = wsi + I_CSRP;
    int* csrN = wsi + I_CSRN;
    int* part = wsi + I_PART;
    unsigned short* h_pos = (unsigned short*)(ws + F_BUF);
    unsigned short* h_neg = (unsigned short*)(ws + F_BUF + H_SLOTS);
    float* pn = ws + F_PN;
    unsigned short* zb = (unsigned short*)(ws + F_ZB);
    float* z = out + 1;

    hipMemsetAsync(ws, 0, (size_t)(16 + 4 * N_NODES) * sizeof(float), stream);

    count_kernel<<<(EP_N + EN_N + 255) / 256, 256, 0, stream>>>(pe, ne, cntP, cntN);
    scan_p1<<<2 * SBLK, 512, 0, stream>>>(cntP, cntN, part);
    scan_p2<<<1, 512, 0, stream>>>(part);
    scan_p3<<<2 * SBLK, 512, 0, stream>>>(cntP, cntN, part, offP, offN);
    fill_kernel<<<(EP_N + EN_N + 255) / 256, 256, 0, stream>>>(pe, ne, offP, offN,
                                                               curP, curN, csrP, csrN);

    base_fused<<<NODE_BLOCKS, 512, 0, stream>>>(X, offP, csrP, W_pos0, b_pos0, h_pos);
    base_fused<<<NODE_BLOCKS, 512, 0, stream>>>(X, offN, csrN, W_neg0, b_neg0, h_neg);

    deep_fused<<<NODE_BLOCKS, 512, 0, stream>>>(h_pos, h_neg, offP, csrP, offN, csrN,
                                                W_pos1, b_pos1, z, 0);
    deep_fused<<<NODE_BLOCKS, 512, 0, stream>>>(h_neg, h_pos, offP, csrP, offN, csrN,
                                                W_neg1, b_neg1, z, 32);

    node_proj<<<(N_NODES + 3) / 4, 256, 0, stream>>>(z, W_reg, zb, pn);
    loss2_kernel<<<1024, 256, 0, stream>>>(zb, pn, pe, ne, ps, ns, target, acc);
    finalize_kernel<<<1, 1, 0, stream>>>(acc, out);
}

// Round 5
// 490.431 us; speedup vs baseline: 3.5829x; 1.0902x over previous
//
#include <hip/hip_runtime.h>
#include <cstdint>

#define N_NODES 100000
#define EP_N 400000
#define EN_N 400000
#define NODE_BLOCKS ((N_NODES + 63) / 64)
#define SCHUNK 512
#define SBLK ((N_NODES + SCHUNK - 1) / SCHUNK)

// ws layout (in 4-byte units)
#define ACC_OFF 0                      // 16 floats
#define I_CNTP 16
#define I_CNTN (I_CNTP + N_NODES)
#define I_CURP (I_CNTN + N_NODES)
#define I_CURN (I_CURP + N_NODES)
#define I_OFFP (I_CURN + N_NODES)
#define I_OFFN (I_OFFP + N_NODES + 1)
#define I_CSRP (I_OFFN + N_NODES + 1)
#define I_CSRN (I_CSRP + EP_N)
#define I_PART (I_CSRN + EN_N)
#define F_XB (((I_PART + 2 * SBLK) + 15) & ~15)   // xb: N*64 ushort = N*32 slots
#define F_HB (F_XB + 32 * N_NODES)                // hboth: N*128 ushort = N*64 slots
#define F_PN (F_HB + 64 * N_NODES)                // pn: N*8 floats
#define F_ZB (F_PN + 8 * N_NODES)                 // zb: N*64 ushort = N*32 slots

__device__ inline float bf2f(unsigned short u) {
    return __uint_as_float((unsigned)u << 16);
}
__device__ inline unsigned short f2bf(float v) {
    unsigned u = __float_as_uint(v);
    return (unsigned short)((u + 0x7FFFu + ((u >> 16) & 1u)) >> 16);
}
__device__ inline float lo_bf(unsigned u) { return __uint_as_float(u << 16); }
__device__ inline float hi_bf(unsigned u) { return __uint_as_float(u & 0xFFFF0000u); }

__global__ void x_to_bf(const float* __restrict__ X, unsigned short* __restrict__ xb) {
    int i = blockIdx.x * 256 + threadIdx.x;
    if (i < N_NODES * 16) {
        float4 v = ((const float4*)X)[i];
        ushort4 o;
        o.x = f2bf(v.x); o.y = f2bf(v.y); o.z = f2bf(v.z); o.w = f2bf(v.w);
        ((ushort4*)xb)[i] = o;
    }
}

__global__ void count_kernel(const int* __restrict__ pe, const int* __restrict__ ne,
                             int* cp, int* cn) {
    int i = blockIdx.x * 256 + threadIdx.x;
    if (i < EP_N) {
        atomicAdd(&cp[pe[i]], 1);
    } else if (i < EP_N + EN_N) {
        atomicAdd(&cn[ne[i - EP_N]], 1);
    }
}

__global__ __launch_bounds__(512) void scan_p1(const int* __restrict__ cntP,
                                               const int* __restrict__ cntN,
                                               int* part) {
    int l = blockIdx.x < SBLK ? 0 : 1;
    int blk = blockIdx.x - l * SBLK;
    const int* cnt = l == 0 ? cntP : cntN;
    int idx = blk * SCHUNK + threadIdx.x;
    int v = idx < N_NODES ? cnt[idx] : 0;
    __shared__ int tmp[512];
    tmp[threadIdx.x] = v;
    __syncthreads();
    for (int d = 256; d > 0; d >>= 1) {
        if (threadIdx.x < d) tmp[threadIdx.x] += tmp[threadIdx.x + d];
        __syncthreads();
    }
    if (threadIdx.x == 0) part[l * SBLK + blk] = tmp[0];
}

__global__ __launch_bounds__(512) void scan_p2(int* part) {
    int t = threadIdx.x;
    int l = t >> 8, idx = t & 255;
    int v = idx < SBLK ? part[l * SBLK + idx] : 0;
    __shared__ int tmp[512];
    int sb = l << 8;
    tmp[sb + idx] = v;
    __syncthreads();
    for (int d = 1; d < 256; d <<= 1) {
        int x = (idx >= d) ? tmp[sb + idx - d] : 0;
        __syncthreads();
        tmp[sb + idx] += x;
        __syncthreads();
    }
    if (idx < SBLK) part[l * SBLK + idx] = tmp[sb + idx] - v;
}

__global__ __launch_bounds__(512) void scan_p3(const int* __restrict__ cntP,
                                               const int* __restrict__ cntN,
                                               const int* __restrict__ part,
                                               int* offP, int* offN) {
    int l = blockIdx.x < SBLK ? 0 : 1;
    int blk = blockIdx.x - l * SBLK;
    const int* cnt = l == 0 ? cntP : cntN;
    int* off = l == 0 ? offP : offN;
    int base = part[l * SBLK + blk];
    int t = threadIdx.x;
    int gidx = blk * SCHUNK + t;
    int c = gidx < N_NODES ? cnt[gidx] : 0;
    __shared__ int tmp[512];
    tmp[t] = c;
    __syncthreads();
    for (int d = 1; d < 512; d <<= 1) {
        int x = (t >= d) ? tmp[t - d] : 0;
        __syncthreads();
        tmp[t] += x;
        __syncthreads();
    }
    int incl = tmp[t];
    if (gidx < N_NODES) off[gidx] = base + incl - c;
    if (gidx == N_NODES - 1) off[N_NODES] = base + incl;
}

__global__ void fill_kernel(const int* __restrict__ pe, const int* __restrict__ ne,
                            const int* __restrict__ offP, const int* __restrict__ offN,
                            int* curP, int* curN, int* csrP, int* csrN) {
    int e = blockIdx.x * 256 + threadIdx.x;
    if (e < EP_N) {
        int row = pe[e], col = pe[EP_N + e];
        int slot = atomicAdd(&curP[row], 1);
        csrP[offP[row] + slot] = col;
    } else if (e < EP_N + EN_N) {
        int e2 = e - EP_N;
        int row = ne[e2], col = ne[EN_N + e2];
        int slot = atomicAdd(&curN[row], 1);
        csrN[offN[row] + slot] = col;
    }
}

// gather-mean of bf16 rows (2B/lane)
__device__ inline float gather_mean_b(const unsigned short* __restrict__ src,
                                      const int* __restrict__ csr,
                                      int st, int en, int lane) {
    float s0 = 0.f, s1 = 0.f, s2 = 0.f, s3 = 0.f;
    for (int p = st; p < en; p += 4) {
        int c0 = csr[p];
        int c1 = csr[min(p + 1, en - 1)];
        int c2 = csr[min(p + 2, en - 1)];
        int c3 = csr[min(p + 3, en - 1)];
        float v0 = bf2f(src[c0 * 64 + lane]);
        float v1 = bf2f(src[c1 * 64 + lane]);
        float v2 = bf2f(src[c2 * 64 + lane]);
        float v3 = bf2f(src[c3 * 64 + lane]);
        s0 += v0;
        s1 += (p + 1 < en) ? v1 : 0.f;
        s2 += (p + 2 < en) ? v2 : 0.f;
        s3 += (p + 3 < en) ? v3 : 0.f;
    }
    return ((s0 + s1) + (s2 + s3)) / fmaxf((float)(en - st), 1.0f);
}

// gather-mean of interleaved (hp,hn) u32 rows -> two means
__device__ inline void gather2(const unsigned* __restrict__ hb32,
                               const int* __restrict__ csr,
                               int st, int en, int lane, float& mp, float& mn) {
    float p0 = 0.f, p1 = 0.f, p2 = 0.f, p3 = 0.f;
    float n0 = 0.f, n1 = 0.f, n2 = 0.f, n3 = 0.f;
    for (int p = st; p < en; p += 4) {
        int c0 = csr[p];
        int c1 = csr[min(p + 1, en - 1)];
        int c2 = csr[min(p + 2, en - 1)];
        int c3 = csr[min(p + 3, en - 1)];
        unsigned v0 = hb32[c0 * 64 + lane];
        unsigned v1 = hb32[c1 * 64 + lane];
        unsigned v2 = hb32[c2 * 64 + lane];
        unsigned v3 = hb32[c3 * 64 + lane];
        p0 += lo_bf(v0); n0 += hi_bf(v0);
        p1 += (p + 1 < en) ? lo_bf(v1) : 0.f;
        n1 += (p + 1 < en) ? hi_bf(v1) : 0.f;
        p2 += (p + 2 < en) ? lo_bf(v2) : 0.f;
        n2 += (p + 2 < en) ? hi_bf(v2) : 0.f;
        p3 += (p + 3 < en) ? lo_bf(v3) : 0.f;
        n3 += (p + 3 < en) ? hi_bf(v3) : 0.f;
    }
    float d = 1.0f / fmaxf((float)(en - st), 1.0f);
    mp = ((p0 + p1) + (p2 + p3)) * d;
    mn = ((n0 + n1) + (n2 + n3)) * d;
}

// both base layers fused; writes h interleaved [node][dim]{hp,hn} bf16
__global__ __launch_bounds__(512) void base_both(
    const unsigned short* __restrict__ xb,
    const int* __restrict__ offP, const int* __restrict__ csrP,
    const int* __restrict__ offN, const int* __restrict__ csrN,
    const float* __restrict__ Wp0, const float* __restrict__ bp0,
    const float* __restrict__ Wn0, const float* __restrict__ bn0,
    unsigned short* __restrict__ hboth) {
    __shared__ float lds[64 * 193];  // row: [gmP(64) | gmN(64) | X(64)]
    int tid = threadIdx.x, lane = tid & 63, w = tid >> 6;
    int base = blockIdx.x * 64;
    for (int r = w * 8; r < w * 8 + 8; ++r) {
        int node = base + r;
        float gP = 0.f, gN = 0.f, sv = 0.f;
        if (node < N_NODES) {
            gP = gather_mean_b(xb, csrP, offP[node], offP[node + 1], lane);
            gN = gather_mean_b(xb, csrN, offN[node], offN[node + 1], lane);
            sv = bf2f(xb[node * 64 + lane]);
        }
        lds[r * 193 + lane] = gP;
        lds[r * 193 + 64 + lane] = gN;
        lds[r * 193 + 128 + lane] = sv;
    }
    __syncthreads();
    int wu = __builtin_amdgcn_readfirstlane(w);
    const float* WP = Wp0 + wu * 8;
    const float* WN = Wn0 + wu * 8;
    float accP[8], accN[8];
#pragma unroll
    for (int j = 0; j < 8; ++j) { accP[j] = 0.f; accN[j] = 0.f; }
    const float* row = &lds[lane * 193];
    for (int k = 0; k < 64; ++k) {
        float vP = row[k], vN = row[64 + k], vX = row[128 + k];
#pragma unroll
        for (int j = 0; j < 8; ++j) {
            accP[j] = fmaf(vP, WP[k * 64 + j], accP[j]);
            accP[j] = fmaf(vX, WP[(64 + k) * 64 + j], accP[j]);
            accN[j] = fmaf(vN, WN[k * 64 + j], accN[j]);
            accN[j] = fmaf(vX, WN[(64 + k) * 64 + j], accN[j]);
        }
    }
#pragma unroll
    for (int j = 0; j < 8; ++j) {
        accP[j] = tanhf(accP[j] + bp0[wu * 8 + j]);
        accN[j] = tanhf(accN[j] + bn0[wu * 8 + j]);
    }
    __syncthreads();
    float* ot = lds;  // [64][130]: cols 0..63 pos, 64..127 neg
#pragma unroll
    for (int j = 0; j < 8; ++j) {
        ot[lane * 130 + wu * 8 + j] = accP[j];
        ot[lane * 130 + 64 + wu * 8 + j] = accN[j];
    }
    __syncthreads();
    unsigned* hb32 = (unsigned*)hboth;
    for (int i = tid; i < 64 * 64; i += 512) {
        int rr = i >> 6, c = i & 63;
        int node = base + rr;
        if (node < N_NODES) {
            unsigned lo = f2bf(ot[rr * 130 + c]);
            unsigned hi = f2bf(ot[rr * 130 + 64 + c]);
            hb32[node * 64 + c] = lo | (hi << 16);
        }
    }
}

// both deep layers fused + z/zb/pn epilogue
__global__ __launch_bounds__(512) void deep_both(
    const unsigned short* __restrict__ hb,
    const int* __restrict__ offP, const int* __restrict__ csrP,
    const int* __restrict__ offN, const int* __restrict__ csrN,
    const float* __restrict__ Wp1, const float* __restrict__ bp1,
    const float* __restrict__ Wn1, const float* __restrict__ bn1,
    const float* __restrict__ Wreg, float* __restrict__ z,
    unsigned short* __restrict__ zbuf, float* __restrict__ pn) {
    __shared__ unsigned short lds[64 * 386];  // row(ushort): [posIn 0..191 | negIn 192..383]
    int tid = threadIdx.x, lane = tid & 63, w = tid >> 6;
    int base = blockIdx.x * 64;
    const unsigned* hb32 = (const unsigned*)hb;
    for (int r = w * 8; r < w * 8 + 8; ++r) {
        int node = base + r;
        float gPp = 0.f, gPn = 0.f, gNp = 0.f, gNn = 0.f, sp = 0.f, sn = 0.f;
        if (node < N_NODES) {
            gather2(hb32, csrP, offP[node], offP[node + 1], lane, gPp, gPn);
            gather2(hb32, csrN, offN[node], offN[node + 1], lane, gNp, gNn);
            unsigned self = hb32[node * 64 + lane];
            sp = lo_bf(self);
            sn = hi_bf(self);
        }
        unsigned short* rp = &lds[r * 386];
        rp[lane] = f2bf(gPp);        // posIn[0:64]   = gm(h_pos, csrP)
        rp[64 + lane] = f2bf(gNn);   // posIn[64:128] = gm(h_neg, csrN)
        rp[128 + lane] = f2bf(sp);   // posIn[128:192]= h_pos self
        rp[192 + lane] = f2bf(gPn);  // negIn[0:64]   = gm(h_neg, csrP)
        rp[256 + lane] = f2bf(gNp);  // negIn[64:128] = gm(h_pos, csrN)
        rp[320 + lane] = f2bf(sn);   // negIn[128:192]= h_neg self
    }
    __syncthreads();
    int wu = __builtin_amdgcn_readfirstlane(w);
    const float* WP = Wp1 + wu * 4;
    const float* WN = Wn1 + wu * 4;
    float accP[4], accN[4];
#pragma unroll
    for (int j = 0; j < 4; ++j) { accP[j] = 0.f; accN[j] = 0.f; }
    const unsigned* rowu = (const unsigned*)&lds[lane * 386];
    for (int kk = 0; kk < 96; ++kk) {
        unsigned up = rowu[kk];
        unsigned un = rowu[96 + kk];
        float p0 = lo_bf(up), p1 = hi_bf(up);
        float q0 = lo_bf(un), q1 = hi_bf(un);
#pragma unroll
        for (int j = 0; j < 4; ++j) {
            accP[j] = fmaf(p0, WP[(2 * kk) * 32 + j], accP[j]);
            accP[j] = fmaf(p1, WP[(2 * kk + 1) * 32 + j], accP[j]);
            accN[j] = fmaf(q0, WN[(2 * kk) * 32 + j], accN[j]);
            accN[j] = fmaf(q1, WN[(2 * kk + 1) * 32 + j], accN[j]);
        }
    }
#pragma unroll
    for (int j = 0; j < 4; ++j) {
        accP[j] = tanhf(accP[j] + bp1[wu * 4 + j]);
        accN[j] = tanhf(accN[j] + bn1[wu * 4 + j]);
    }
    __syncthreads();
    float* ot = (float*)lds;  // [64][65]: cols 0..31 pos, 32..63 neg
#pragma unroll
    for (int j = 0; j < 4; ++j) {
        ot[lane * 65 + wu * 4 + j] = accP[j];
        ot[lane * 65 + 32 + wu * 4 + j] = accN[j];
    }
    __syncthreads();
    // epilogue: z write + bf16 copy + per-node loss projections
    for (int r = w * 8; r < w * 8 + 8; ++r) {
        int node = base + r;
        if (node >= N_NODES) break;
        float v = ot[r * 65 + lane];
        z[node * 64 + lane] = v;
        unsigned short rb = f2bf(v);
        zbuf[node * 64 + lane] = rb;
        float vb = bf2f(rb);
        float u0 = vb * Wreg[lane * 2 + 0];
        float u1 = vb * Wreg[lane * 2 + 1];
        float v0 = vb * Wreg[128 + lane * 2 + 0];
        float v1 = vb * Wreg[128 + lane * 2 + 1];
        float s = vb * vb;
#pragma unroll
        for (int off = 32; off; off >>= 1) {
            u0 += __shfl_xor(u0, off);
            u1 += __shfl_xor(u1, off);
            v0 += __shfl_xor(v0, off);
            v1 += __shfl_xor(v1, off);
            s += __shfl_xor(s, off);
        }
        if (lane == 0) {
            float4 st = {u0, u1, v0, v1};
            *(float4*)(pn + node * 8) = st;
            pn[node * 8 + 4] = s;
        }
    }
}

// 4 edges per wave (16-lane groups): cross-dots + precomputed node scalars
__global__ __launch_bounds__(256) void loss2_kernel(
    const unsigned short* __restrict__ zb, const float* __restrict__ pn,
    const int* __restrict__ pe, const int* __restrict__ ne,
    const int* __restrict__ ps, const int* __restrict__ ns,
    const int* __restrict__ tgt, float* acc) {
    int tid = threadIdx.x;
    int lane = tid & 63;
    int g = lane >> 4, sub = lane & 15;
    int wid = (blockIdx.x * 256 + tid) >> 6;
    int nw = (gridDim.x * 256) >> 6;
    float s_p = 0.f, s_n = 0.f, s_r = 0.f;
    const float q = 0.0625f;
    for (int eb = wid * 4; eb < EP_N + EN_N; eb += nw * 4) {
        int e = eb + g;
        bool valid = e < EP_N + EN_N;
        bool isp = e < EP_N;
        int i = 0, j = 0, k = 0, t = 0;
        if (valid) {
            if (isp) {
                i = pe[e]; j = pe[EP_N + e]; k = ps[e];
            } else {
                int e2 = e - EP_N;
                i = ne[e2]; j = ne[EN_N + e2]; k = ns[e2];
            }
            t = tgt[e];
        }
        const ushort4 zi4 = *(const ushort4*)(zb + ((long long)i << 6) + (sub << 2));
        const ushort4 zj4 = *(const ushort4*)(zb + ((long long)j << 6) + (sub << 2));
        const ushort4 zk4 = *(const ushort4*)(zb + ((long long)k << 6) + (sub << 2));
        float zi0 = bf2f(zi4.x), zi1 = bf2f(zi4.y), zi2 = bf2f(zi4.z), zi3 = bf2f(zi4.w);
        float zj0 = bf2f(zj4.x), zj1 = bf2f(zj4.y), zj2 = bf2f(zj4.z), zj3 = bf2f(zj4.w);
        float zk0 = bf2f(zk4.x), zk1 = bf2f(zk4.y), zk2 = bf2f(zk4.z), zk3 = bf2f(zk4.w);
        float d1 = zi0 * zj0 + zi1 * zj1 + zi2 * zj2 + zi3 * zj3;
        float d2 = zj0 * zk0 + zj1 * zk1 + zj2 * zk2 + zj3 * zk3;
#pragma unroll
        for (int off = 1; off < 16; off <<= 1) {
            d1 += __shfl_xor(d1, off);
            d2 += __shfl_xor(d2, off);
        }
        if (valid) {
            const float* pni = pn + ((long long)i << 3);
            const float* pnj = pn + ((long long)j << 3);
            float u0 = pni[0], u1 = pni[1], si = pni[4];
            float v0 = pnj[2], v1 = pnj[3], sj = pnj[4];
            float sk = pn[((long long)k << 3) + 4];
            float nij = si + sj - 2.f * d1;
            float nik = sj + sk - 2.f * d2;
            float tri = fmaxf(nij - nik, 0.f);
            float l0 = u0 + v0, l1 = u1 + v1;
            float m = fmaxf(l0, l1);
            float lse = m + logf(expf(l0 - m) + expf(l1 - m));
            float r = lse - (t ? l1 : l0);
            s_r += r * q;
            if (isp) s_p += tri * q; else s_n += tri * q;
        }
    }
#pragma unroll
    for (int off = 32; off; off >>= 1) {
        s_p += __shfl_xor(s_p, off);
        s_n += __shfl_xor(s_n, off);
        s_r += __shfl_xor(s_r, off);
    }
    __shared__ float red[3][4];
    int w = tid >> 6;
    if (lane == 0) {
        red[0][w] = s_p; red[1][w] = s_n; red[2][w] = s_r;
    }
    __syncthreads();
    if (tid == 0) {
        atomicAdd(&acc[0], red[0][0] + red[0][1] + red[0][2] + red[0][3]);
        atomicAdd(&acc[1], red[1][0] + red[1][1] + red[1][2] + red[1][3]);
        atomicAdd(&acc[2], red[2][0] + red[2][1] + red[2][2] + red[2][3]);
    }
}

__global__ void finalize_kernel(const float* __restrict__ acc, float* out) {
    out[0] = acc[2] / (float)(EP_N + EN_N) +
             1.0f * (acc[0] / (float)EP_N + acc[1] / (float)EN_N);
}

extern "C" void kernel_launch(void* const* d_in, const int* in_sizes, int n_in,
                              void* d_out, int out_size, void* d_ws, size_t ws_size,
                              hipStream_t stream) {
    const float* X = (const float*)d_in[0];
    const float* W_pos0 = (const float*)d_in[1];
    const float* b_pos0 = (const float*)d_in[2];
    const float* W_neg0 = (const float*)d_in[3];
    const float* b_neg0 = (const float*)d_in[4];
    const float* W_pos1 = (const float*)d_in[5];
    const float* b_pos1 = (const float*)d_in[6];
    const float* W_neg1 = (const float*)d_in[7];
    const float* b_neg1 = (const float*)d_in[8];
    const float* W_reg = (const float*)d_in[9];
    const int* pe = (const int*)d_in[10];
    const int* ne = (const int*)d_in[11];
    const int* target = (const int*)d_in[12];
    const int* ps = (const int*)d_in[13];
    const int* ns = (const int*)d_in[14];
    float* out = (float*)d_out;
    float* ws = (float*)d_ws;
    int* wsi = (int*)d_ws;

    float* acc = ws + ACC_OFF;
    int* cntP = wsi + I_CNTP;
    int* cntN = wsi + I_CNTN;
    int* curP = wsi + I_CURP;
    int* curN = wsi + I_CURN;
    int* offP = wsi + I_OFFP;
    int* offN = wsi + I_OFFN;
    int* csrP = wsi + I_CSRP;
    int* csrN = wsi + I_CSRN;
    int* part = wsi + I_PART;
    unsigned short* xb = (unsigned short*)(ws + F_XB);
    unsigned short* hboth = (unsigned short*)(ws + F_HB);
    float* pn = ws + F_PN;
    unsigned short* zb = (unsigned short*)(ws + F_ZB);
    float* z = out + 1;

    hipMemsetAsync(ws, 0, (size_t)(16 + 4 * N_NODES) * sizeof(float), stream);

    x_to_bf<<<(N_NODES * 16 + 255) / 256, 256, 0, stream>>>(X, xb);
    count_kernel<<<(EP_N + EN_N + 255) / 256, 256, 0, stream>>>(pe, ne, cntP, cntN);
    scan_p1<<<2 * SBLK, 512, 0, stream>>>(cntP, cntN, part);
    scan_p2<<<1, 512, 0, stream>>>(part);
    scan_p3<<<2 * SBLK, 512, 0, stream>>>(cntP, cntN, part, offP, offN);
    fill_kernel<<<(EP_N + EN_N + 255) / 256, 256, 0, stream>>>(pe, ne, offP, offN,
                                                               curP, curN, csrP, csrN);

    base_both<<<NODE_BLOCKS, 512, 0, stream>>>(xb, offP, csrP, offN, csrN,
                                               W_pos0, b_pos0, W_neg0, b_neg0, hboth);
    deep_both<<<NODE_BLOCKS, 512, 0, stream>>>(hboth, offP, csrP, offN, csrN,
                                               W_pos1, b_pos1, W_neg1, b_neg1,
                                               W_reg, z, zb, pn);

    loss2_kernel<<<2048, 256, 0, stream>>>(zb, pn, pe, ne, ps, ns, target, acc);
    finalize_kernel<<<1, 1, 0, stream>>>(acc, out);
}

// Round 6
// 425.446 us; speedup vs baseline: 4.1302x; 1.1527x over previous
//
#include <hip/hip_runtime.h>
#include <cstdint>

#define N_NODES 100000
#define EP_N 400000
#define EN_N 400000
#define NODE_BLOCKS ((N_NODES + 63) / 64)
#define SCHUNK 512
#define SBLK ((N_NODES + SCHUNK - 1) / SCHUNK)

#define BSTR 264   // base LDS row: [gP(64) | X(64) | gN(64) | X(64)] + 8 pad (ushorts)
#define DSTR 392   // deep LDS row: [posIn(192) | negIn(192)] + 8 pad (ushorts)

// ws layout (in 4-byte units)
#define ACC_OFF 0
#define I_CNTP 16
#define I_CNTN (I_CNTP + N_NODES)
#define I_CURP (I_CNTN + N_NODES)
#define I_CURN (I_CURP + N_NODES)
#define I_OFFP (I_CURN + N_NODES)
#define I_OFFN (I_OFFP + N_NODES + 1)
#define I_CSRP (I_OFFN + N_NODES + 1)
#define I_CSRN (I_CSRP + EP_N)
#define I_PART (I_CSRN + EN_N)
#define F_XB (((I_PART + 2 * SBLK) + 15) & ~15)   // xb: N*64 ushort
#define F_HB (F_XB + 32 * N_NODES)                // hboth: N*64 u32
#define F_PN (F_HB + 64 * N_NODES)                // pn: N*8 floats
#define F_ZB (F_PN + 8 * N_NODES)                 // zb: N*64 ushort
#define F_WT (((F_ZB + 32 * N_NODES) + 15) & ~15) // wt: 28672 ushorts (bf16 weights)
// wt ushort offsets: Wt0p 0, Wt0n 8192, Wt1p 16384, Wt1n 22528

typedef __attribute__((ext_vector_type(8))) short sh8;
typedef __attribute__((ext_vector_type(4))) float f32x4;

__device__ inline float bf2f(unsigned short u) {
    return __uint_as_float((unsigned)u << 16);
}
__device__ inline unsigned short f2bf(float v) {
    unsigned u = __float_as_uint(v);
    return (unsigned short)((u + 0x7FFFu + ((u >> 16) & 1u)) >> 16);
}
__device__ inline float lo_bf(unsigned u) { return __uint_as_float(u << 16); }
__device__ inline float hi_bf(unsigned u) { return __uint_as_float(u & 0xFFFF0000u); }

__global__ void x_to_bf(const float* __restrict__ X, unsigned short* __restrict__ xb) {
    int i = blockIdx.x * 256 + threadIdx.x;
    if (i < N_NODES * 16) {
        float4 v = ((const float4*)X)[i];
        ushort4 o;
        o.x = f2bf(v.x); o.y = f2bf(v.y); o.z = f2bf(v.z); o.w = f2bf(v.w);
        ((ushort4*)xb)[i] = o;
    }
}

// transpose + bf16-ify the 4 weight matrices: Wt[n][k] = W[k][n]
__global__ void wprep(const float* __restrict__ W0p, const float* __restrict__ W0n,
                      const float* __restrict__ W1p, const float* __restrict__ W1n,
                      unsigned short* __restrict__ wt) {
    int i = blockIdx.x * 256 + threadIdx.x;
    if (i < 8192) {
        int n = i >> 7, k = i & 127;
        wt[i] = f2bf(W0p[k * 64 + n]);
    } else if (i < 16384) {
        int j = i - 8192; int n = j >> 7, k = j & 127;
        wt[i] = f2bf(W0n[k * 64 + n]);
    } else if (i < 22528) {
        int j = i - 16384; int n = j / 192, k = j - n * 192;
        wt[i] = f2bf(W1p[k * 32 + n]);
    } else if (i < 28672) {
        int j = i - 22528; int n = j / 192, k = j - n * 192;
        wt[i] = f2bf(W1n[k * 32 + n]);
    }
}

__global__ void count_kernel(const int* __restrict__ pe, const int* __restrict__ ne,
                             int* cp, int* cn) {
    int i = blockIdx.x * 256 + threadIdx.x;
    if (i < EP_N) {
        atomicAdd(&cp[pe[i]], 1);
    } else if (i < EP_N + EN_N) {
        atomicAdd(&cn[ne[i - EP_N]], 1);
    }
}

__global__ __launch_bounds__(512) void scan_p1(const int* __restrict__ cntP,
                                               const int* __restrict__ cntN,
                                               int* part) {
    int l = blockIdx.x < SBLK ? 0 : 1;
    int blk = blockIdx.x - l * SBLK;
    const int* cnt = l == 0 ? cntP : cntN;
    int idx = blk * SCHUNK + threadIdx.x;
    int v = idx < N_NODES ? cnt[idx] : 0;
    __shared__ int tmp[512];
    tmp[threadIdx.x] = v;
    __syncthreads();
    for (int d = 256; d > 0; d >>= 1) {
        if (threadIdx.x < d) tmp[threadIdx.x] += tmp[threadIdx.x + d];
        __syncthreads();
    }
    if (threadIdx.x == 0) part[l * SBLK + blk] = tmp[0];
}

__global__ __launch_bounds__(512) void scan_p2(int* part) {
    int t = threadIdx.x;
    int l = t >> 8, idx = t & 255;
    int v = idx < SBLK ? part[l * SBLK + idx] : 0;
    __shared__ int tmp[512];
    int sb = l << 8;
    tmp[sb + idx] = v;
    __syncthreads();
    for (int d = 1; d < 256; d <<= 1) {
        int x = (idx >= d) ? tmp[sb + idx - d] : 0;
        __syncthreads();
        tmp[sb + idx] += x;
        __syncthreads();
    }
    if (idx < SBLK) part[l * SBLK + idx] = tmp[sb + idx] - v;
}

__global__ __launch_bounds__(512) void scan_p3(const int* __restrict__ cntP,
                                               const int* __restrict__ cntN,
                                               const int* __restrict__ part,
                                               int* offP, int* offN) {
    int l = blockIdx.x < SBLK ? 0 : 1;
    int blk = blockIdx.x - l * SBLK;
    const int* cnt = l == 0 ? cntP : cntN;
    int* off = l == 0 ? offP : offN;
    int base = part[l * SBLK + blk];
    int t = threadIdx.x;
    int gidx = blk * SCHUNK + t;
    int c = gidx < N_NODES ? cnt[gidx] : 0;
    __shared__ int tmp[512];
    tmp[t] = c;
    __syncthreads();
    for (int d = 1; d < 512; d <<= 1) {
        int x = (t >= d) ? tmp[t - d] : 0;
        __syncthreads();
        tmp[t] += x;
        __syncthreads();
    }
    int incl = tmp[t];
    if (gidx < N_NODES) off[gidx] = base + incl - c;
    if (gidx == N_NODES - 1) off[N_NODES] = base + incl;
}

__global__ void fill_kernel(const int* __restrict__ pe, const int* __restrict__ ne,
                            const int* __restrict__ offP, const int* __restrict__ offN,
                            int* curP, int* curN, int* csrP, int* csrN) {
    int e = blockIdx.x * 256 + threadIdx.x;
    if (e < EP_N) {
        int row = pe[e], col = pe[EP_N + e];
        int slot = atomicAdd(&curP[row], 1);
        csrP[offP[row] + slot] = col;
    } else if (e < EP_N + EN_N) {
        int e2 = e - EP_N;
        int row = ne[e2], col = ne[EN_N + e2];
        int slot = atomicAdd(&curN[row], 1);
        csrN[offN[row] + slot] = col;
    }
}

// gather-mean of bf16 rows (2B/lane)
__device__ inline float gather_mean_b(const unsigned short* __restrict__ src,
                                      const int* __restrict__ csr,
                                      int st, int en, int lane) {
    float s0 = 0.f, s1 = 0.f, s2 = 0.f, s3 = 0.f;
    for (int p = st; p < en; p += 4) {
        int c0 = csr[p];
        int c1 = csr[min(p + 1, en - 1)];
        int c2 = csr[min(p + 2, en - 1)];
        int c3 = csr[min(p + 3, en - 1)];
        float v0 = bf2f(src[c0 * 64 + lane]);
        float v1 = bf2f(src[c1 * 64 + lane]);
        float v2 = bf2f(src[c2 * 64 + lane]);
        float v3 = bf2f(src[c3 * 64 + lane]);
        s0 += v0;
        s1 += (p + 1 < en) ? v1 : 0.f;
        s2 += (p + 2 < en) ? v2 : 0.f;
        s3 += (p + 3 < en) ? v3 : 0.f;
    }
    return ((s0 + s1) + (s2 + s3)) / fmaxf((float)(en - st), 1.0f);
}

// gather-mean of interleaved (hp,hn) u32 rows -> two means
__device__ inline void gather2(const unsigned* __restrict__ hb32,
                               const int* __restrict__ csr,
                               int st, int en, int lane, float& mp, float& mn) {
    float p0 = 0.f, p1 = 0.f, p2 = 0.f, p3 = 0.f;
    float n0 = 0.f, n1 = 0.f, n2 = 0.f, n3 = 0.f;
    for (int p = st; p < en; p += 4) {
        int c0 = csr[p];
        int c1 = csr[min(p + 1, en - 1)];
        int c2 = csr[min(p + 2, en - 1)];
        int c3 = csr[min(p + 3, en - 1)];
        unsigned v0 = hb32[c0 * 64 + lane];
        unsigned v1 = hb32[c1 * 64 + lane];
        unsigned v2 = hb32[c2 * 64 + lane];
        unsigned v3 = hb32[c3 * 64 + lane];
        p0 += lo_bf(v0); n0 += hi_bf(v0);
        p1 += (p + 1 < en) ? lo_bf(v1) : 0.f;
        n1 += (p + 1 < en) ? hi_bf(v1) : 0.f;
        p2 += (p + 2 < en) ? lo_bf(v2) : 0.f;
        n2 += (p + 2 < en) ? hi_bf(v2) : 0.f;
        p3 += (p + 3 < en) ? lo_bf(v3) : 0.f;
        n3 += (p + 3 < en) ? hi_bf(v3) : 0.f;
    }
    float d = 1.0f / fmaxf((float)(en - st), 1.0f);
    mp = ((p0 + p1) + (p2 + p3)) * d;
    mn = ((n0 + n1) + (n2 + n3)) * d;
}

// both base layers: gather (bf16) -> MFMA GEMM -> tanh -> interleaved bf16 h
__global__ __launch_bounds__(512) void base_both(
    const unsigned short* __restrict__ xb,
    const int* __restrict__ offP, const int* __restrict__ csrP,
    const int* __restrict__ offN, const int* __restrict__ csrN,
    const unsigned short* __restrict__ wt0,   // [Wt0p(64x128) | Wt0n(64x128)]
    const float* __restrict__ bp0, const float* __restrict__ bn0,
    unsigned short* __restrict__ hboth) {
    __shared__ unsigned short lds[64 * BSTR];  // 33792 B
    int tid = threadIdx.x, lane = tid & 63, w = tid >> 6;
    int base = blockIdx.x * 64;
    for (int r = w * 8; r < w * 8 + 8; ++r) {
        int node = base + r;
        float gP = 0.f, gN = 0.f;
        unsigned short sx = 0;
        if (node < N_NODES) {
            gP = gather_mean_b(xb, csrP, offP[node], offP[node + 1], lane);
            gN = gather_mean_b(xb, csrN, offN[node], offN[node + 1], lane);
            sx = xb[node * 64 + lane];
        }
        unsigned short* rp = &lds[r * BSTR];
        rp[lane] = f2bf(gP);
        rp[64 + lane] = sx;
        rp[128 + lane] = f2bf(gN);
        rp[192 + lane] = sx;
    }
    __syncthreads();
    int wu = __builtin_amdgcn_readfirstlane(w);
    int mt = wu >> 1, half = wu & 1;
    int l15 = lane & 15, kq = lane >> 4;
    const unsigned short* wbase = wt0 + half * 8192;
    f32x4 acc[4];
#pragma unroll
    for (int nt = 0; nt < 4; ++nt) acc[nt] = (f32x4){0.f, 0.f, 0.f, 0.f};
    const unsigned short* arow = &lds[(mt * 16 + l15) * BSTR + half * 128 + kq * 8];
#pragma unroll
    for (int ks = 0; ks < 4; ++ks) {
        sh8 a = *(const sh8*)(arow + ks * 32);
#pragma unroll
        for (int nt = 0; nt < 4; ++nt) {
            sh8 bf = *(const sh8*)(wbase + (nt * 16 + l15) * 128 + ks * 32 + kq * 8);
            acc[nt] = __builtin_amdgcn_mfma_f32_16x16x32_bf16(a, bf, acc[nt], 0, 0, 0);
        }
    }
    __syncthreads();
    float* ht = (float*)lds;  // [64][130]: cols 0..63 pos, 64..127 neg (33280 B)
    const float* bias = half ? bn0 : bp0;
#pragma unroll
    for (int nt = 0; nt < 4; ++nt) {
        int col = nt * 16 + l15;
        float bb = bias[col];
#pragma unroll
        for (int r = 0; r < 4; ++r) {
            int row = mt * 16 + kq * 4 + r;
            ht[row * 130 + half * 64 + col] = tanhf(acc[nt][r] + bb);
        }
    }
    __syncthreads();
    unsigned* hb32 = (unsigned*)hboth;
    for (int i = tid; i < 64 * 64; i += 512) {
        int rr = i >> 6, c = i & 63;
        int node = base + rr;
        if (node < N_NODES) {
            unsigned lo = f2bf(ht[rr * 130 + c]);
            unsigned hi = f2bf(ht[rr * 130 + 64 + c]);
            hb32[node * 64 + c] = lo | (hi << 16);
        }
    }
}

// both deep layers: gather -> MFMA GEMM -> tanh -> z/zb/pn epilogue
__global__ __launch_bounds__(512) void deep_both(
    const unsigned short* __restrict__ hb,
    const int* __restrict__ offP, const int* __restrict__ csrP,
    const int* __restrict__ offN, const int* __restrict__ csrN,
    const unsigned short* __restrict__ wt1,   // [Wt1p(32x192) | Wt1n(32x192)]
    const float* __restrict__ bp1, const float* __restrict__ bn1,
    const float* __restrict__ Wreg, float* __restrict__ z,
    unsigned short* __restrict__ zbuf, float* __restrict__ pn) {
    __shared__ unsigned short lds[64 * DSTR];  // 50176 B
    int tid = threadIdx.x, lane = tid & 63, w = tid >> 6;
    int base = blockIdx.x * 64;
    const unsigned* hb32 = (const unsigned*)hb;
    for (int r = w * 8; r < w * 8 + 8; ++r) {
        int node = base + r;
        float gPp = 0.f, gPn = 0.f, gNp = 0.f, gNn = 0.f, sp = 0.f, sn = 0.f;
        if (node < N_NODES) {
            gather2(hb32, csrP, offP[node], offP[node + 1], lane, gPp, gPn);
            gather2(hb32, csrN, offN[node], offN[node + 1], lane, gNp, gNn);
            unsigned self = hb32[node * 64 + lane];
            sp = lo_bf(self);
            sn = hi_bf(self);
        }
        unsigned short* rp = &lds[r * DSTR];
        rp[lane] = f2bf(gPp);        // posIn[0:64]   = gm(h_pos, csrP)
        rp[64 + lane] = f2bf(gNn);   // posIn[64:128] = gm(h_neg, csrN)
        rp[128 + lane] = f2bf(sp);   // posIn[128:192]= h_pos self
        rp[192 + lane] = f2bf(gPn);  // negIn[0:64]   = gm(h_neg, csrP)
        rp[256 + lane] = f2bf(gNp);  // negIn[64:128] = gm(h_pos, csrN)
        rp[320 + lane] = f2bf(sn);   // negIn[128:192]= h_neg self
    }
    __syncthreads();
    int wu = __builtin_amdgcn_readfirstlane(w);
    int mt = wu >> 1, half = wu & 1;
    int l15 = lane & 15, kq = lane >> 4;
    const unsigned short* wbase = wt1 + half * 6144;
    f32x4 acc[2];
    acc[0] = (f32x4){0.f, 0.f, 0.f, 0.f};
    acc[1] = (f32x4){0.f, 0.f, 0.f, 0.f};
    const unsigned short* arow = &lds[(mt * 16 + l15) * DSTR + half * 192 + kq * 8];
#pragma unroll
    for (int ks = 0; ks < 6; ++ks) {
        sh8 a = *(const sh8*)(arow + ks * 32);
#pragma unroll
        for (int nt = 0; nt < 2; ++nt) {
            sh8 bf = *(const sh8*)(wbase + (nt * 16 + l15) * 192 + ks * 32 + kq * 8);
            acc[nt] = __builtin_amdgcn_mfma_f32_16x16x32_bf16(a, bf, acc[nt], 0, 0, 0);
        }
    }
    __syncthreads();
    float* ot = (float*)lds;  // [64][65]: cols 0..31 pos, 32..63 neg (16640 B)
    const float* bias = half ? bn1 : bp1;
#pragma unroll
    for (int nt = 0; nt < 2; ++nt) {
        int col = nt * 16 + l15;
        float bb = bias[col];
#pragma unroll
        for (int r = 0; r < 4; ++r) {
            int row = mt * 16 + kq * 4 + r;
            ot[row * 65 + half * 32 + col] = tanhf(acc[nt][r] + bb);
        }
    }
    __syncthreads();
    // epilogue: z write + bf16 copy + per-node loss projections
    for (int r = w * 8; r < w * 8 + 8; ++r) {
        int node = base + r;
        if (node >= N_NODES) break;
        float v = ot[r * 65 + lane];
        z[node * 64 + lane] = v;
        unsigned short rb = f2bf(v);
        zbuf[node * 64 + lane] = rb;
        float vb = bf2f(rb);
        float u0 = vb * Wreg[lane * 2 + 0];
        float u1 = vb * Wreg[lane * 2 + 1];
        float v0 = vb * Wreg[128 + lane * 2 + 0];
        float v1 = vb * Wreg[128 + lane * 2 + 1];
        float s = vb * vb;
#pragma unroll
        for (int off = 32; off; off >>= 1) {
            u0 += __shfl_xor(u0, off);
            u1 += __shfl_xor(u1, off);
            v0 += __shfl_xor(v0, off);
            v1 += __shfl_xor(v1, off);
            s += __shfl_xor(s, off);
        }
        if (lane == 0) {
            float4 st = {u0, u1, v0, v1};
            *(float4*)(pn + node * 8) = st;
            pn[node * 8 + 4] = s;
        }
    }
}

// 4 edges per wave (16-lane groups): cross-dots + precomputed node scalars
__global__ __launch_bounds__(256) void loss2_kernel(
    const unsigned short* __restrict__ zb, const float* __restrict__ pn,
    const int* __restrict__ pe, const int* __restrict__ ne,
    const int* __restrict__ ps, const int* __restrict__ ns,
    const int* __restrict__ tgt, float* acc) {
    int tid = threadIdx.x;
    int lane = tid & 63;
    int g = lane >> 4, sub = lane & 15;
    int wid = (blockIdx.x * 256 + tid) >> 6;
    int nw = (gridDim.x * 256) >> 6;
    float s_p = 0.f, s_n = 0.f, s_r = 0.f;
    const float q = 0.0625f;
    for (int eb = wid * 4; eb < EP_N + EN_N; eb += nw * 4) {
        int e = eb + g;
        bool valid = e < EP_N + EN_N;
        bool isp = e < EP_N;
        int i = 0, j = 0, k = 0, t = 0;
        if (valid) {
            if (isp) {
                i = pe[e]; j = pe[EP_N + e]; k = ps[e];
            } else {
                int e2 = e - EP_N;
                i = ne[e2]; j = ne[EN_N + e2]; k = ns[e2];
            }
            t = tgt[e];
        }
        const ushort4 zi4 = *(const ushort4*)(zb + ((long long)i << 6) + (sub << 2));
        const ushort4 zj4 = *(const ushort4*)(zb + ((long long)j << 6) + (sub << 2));
        const ushort4 zk4 = *(const ushort4*)(zb + ((long long)k << 6) + (sub << 2));
        float zi0 = bf2f(zi4.x), zi1 = bf2f(zi4.y), zi2 = bf2f(zi4.z), zi3 = bf2f(zi4.w);
        float zj0 = bf2f(zj4.x), zj1 = bf2f(zj4.y), zj2 = bf2f(zj4.z), zj3 = bf2f(zj4.w);
        float zk0 = bf2f(zk4.x), zk1 = bf2f(zk4.y), zk2 = bf2f(zk4.z), zk3 = bf2f(zk4.w);
        float d1 = zi0 * zj0 + zi1 * zj1 + zi2 * zj2 + zi3 * zj3;
        float d2 = zj0 * zk0 + zj1 * zk1 + zj2 * zk2 + zj3 * zk3;
#pragma unroll
        for (int off = 1; off < 16; off <<= 1) {
            d1 += __shfl_xor(d1, off);
            d2 += __shfl_xor(d2, off);
        }
        if (valid) {
            const float* pni = pn + ((long long)i << 3);
            const float* pnj = pn + ((long long)j << 3);
            float u0 = pni[0], u1 = pni[1], si = pni[4];
            float v0 = pnj[2], v1 = pnj[3], sj = pnj[4];
            float sk = pn[((long long)k << 3) + 4];
            float nij = si + sj - 2.f * d1;
            float nik = sj + sk - 2.f * d2;
            float tri = fmaxf(nij - nik, 0.f);
            float l0 = u0 + v0, l1 = u1 + v1;
            float m = fmaxf(l0, l1);
            float lse = m + logf(expf(l0 - m) + expf(l1 - m));
            float r = lse - (t ? l1 : l0);
            s_r += r * q;
            if (isp) s_p += tri * q; else s_n += tri * q;
        }
    }
#pragma unroll
    for (int off = 32; off; off >>= 1) {
        s_p += __shfl_xor(s_p, off);
        s_n += __shfl_xor(s_n, off);
        s_r += __shfl_xor(s_r, off);
    }
    __shared__ float red[3][4];
    int w = tid >> 6;
    if (lane == 0) {
        red[0][w] = s_p; red[1][w] = s_n; red[2][w] = s_r;
    }
    __syncthreads();
    if (tid == 0) {
        atomicAdd(&acc[0], red[0][0] + red[0][1] + red[0][2] + red[0][3]);
        atomicAdd(&acc[1], red[1][0] + red[1][1] + red[1][2] + red[1][3]);
        atomicAdd(&acc[2], red[2][0] + red[2][1] + red[2][2] + red[2][3]);
    }
}

__global__ void finalize_kernel(const float* __restrict__ acc, float* out) {
    out[0] = acc[2] / (float)(EP_N + EN_N) +
             1.0f * (acc[0] / (float)EP_N + acc[1] / (float)EN_N);
}

extern "C" void kernel_launch(void* const* d_in, const int* in_sizes, int n_in,
                              void* d_out, int out_size, void* d_ws, size_t ws_size,
                              hipStream_t stream) {
    const float* X = (const float*)d_in[0];
    const float* W_pos0 = (const float*)d_in[1];
    const float* b_pos0 = (const float*)d_in[2];
    const float* W_neg0 = (const float*)d_in[3];
    const float* b_neg0 = (const float*)d_in[4];
    const float* W_pos1 = (const float*)d_in[5];
    const float* b_pos1 = (const float*)d_in[6];
    const float* W_neg1 = (const float*)d_in[7];
    const float* b_neg1 = (const float*)d_in[8];
    const float* W_reg = (const float*)d_in[9];
    const int* pe = (const int*)d_in[10];
    const int* ne = (const int*)d_in[11];
    const int* target = (const int*)d_in[12];
    const int* ps = (const int*)d_in[13];
    const int* ns = (const int*)d_in[14];
    float* out = (float*)d_out;
    float* ws = (float*)d_ws;
    int* wsi = (int*)d_ws;

    float* acc = ws + ACC_OFF;
    int* cntP = wsi + I_CNTP;
    int* cntN = wsi + I_CNTN;
    int* curP = wsi + I_CURP;
    int* curN = wsi + I_CURN;
    int* offP = wsi + I_OFFP;
    int* offN = wsi + I_OFFN;
    int* csrP = wsi + I_CSRP;
    int* csrN = wsi + I_CSRN;
    int* part = wsi + I_PART;
    unsigned short* xb = (unsigned short*)(ws + F_XB);
    unsigned short* hboth = (unsigned short*)(ws + F_HB);
    float* pn = ws + F_PN;
    unsigned short* zb = (unsigned short*)(ws + F_ZB);
    unsigned short* wt = (unsigned short*)(ws + F_WT);
    float* z = out + 1;

    hipMemsetAsync(ws, 0, (size_t)(16 + 4 * N_NODES) * sizeof(float), stream);

    x_to_bf<<<(N_NODES * 16 + 255) / 256, 256, 0, stream>>>(X, xb);
    wprep<<<112, 256, 0, stream>>>(W_pos0, W_neg0, W_pos1, W_neg1, wt);
    count_kernel<<<(EP_N + EN_N + 255) / 256, 256, 0, stream>>>(pe, ne, cntP, cntN);
    scan_p1<<<2 * SBLK, 512, 0, stream>>>(cntP, cntN, part);
    scan_p2<<<1, 512, 0, stream>>>(part);
    scan_p3<<<2 * SBLK, 512, 0, stream>>>(cntP, cntN, part, offP, offN);
    fill_kernel<<<(EP_N + EN_N + 255) / 256, 256, 0, stream>>>(pe, ne, offP, offN,
                                                               curP, curN, csrP, csrN);

    base_both<<<NODE_BLOCKS, 512, 0, stream>>>(xb, offP, csrP, offN, csrN,
                                               wt, b_pos0, b_neg0, hboth);
    deep_both<<<NODE_BLOCKS, 512, 0, stream>>>(hboth, offP, csrP, offN, csrN,
                                               wt + 16384, b_pos1, b_neg1,
                                               W_reg, z, zb, pn);

    loss2_kernel<<<2048, 256, 0, stream>>>(zb, pn, pe, ne, ps, ns, target, acc);
    finalize_kernel<<<1, 1, 0, stream>>>(acc, out);
}